// Round 8
// baseline (3423.860 us; speedup 1.0000x reference)
//
#include <hip/hip_runtime.h>
#include <hip/hip_bf16.h>
#include <hip/hip_cooperative_groups.h>
#include <cstdint>

namespace cg = cooperative_groups;

#define D  512
#define D2 1024
#define BB 128
#define SS 128
#define NN 196
#define TT 12

typedef unsigned short u16;

__device__ __forceinline__ float bf2f(u16 h){
  union { unsigned int u; float f; } v; v.u = ((unsigned int)h) << 16; return v.f;
}

__device__ __forceinline__ float LDX(const void* p, size_t i, int isbf){
  if (isbf) return bf2f(((const u16*)p)[i]);
  return ((const float*)p)[i];
}

__device__ __forceinline__ float4 LD4(const void* p, size_t i, int isbf){
  if (isbf){
    ushort4 w = *(const ushort4*)((const u16*)p + i);
    return make_float4(bf2f(w.x), bf2f(w.y), bf2f(w.z), bf2f(w.w));
  }
  return *(const float4*)((const float*)p + i);
}

// ---------------- detect input dtype ----------------
__global__ __launch_bounds__(256) void k_detect(const u16* ctx, int* flag){
  __shared__ int cnt;
  if (threadIdx.x == 0) cnt = 0;
  __syncthreads();
  int bad = 0;
  for (int i = threadIdx.x; i < 8192; i += 256){
    int e = (ctx[i] >> 7) & 0xFF;
    if (e == 0xFF || (e != 0 && (e < 90 || e > 160))) bad++;
  }
  atomicAdd(&cnt, bad);
  __syncthreads();
  if (threadIdx.x == 0) *flag = (cnt > 100) ? 0 : 1;   // 1 = bf16, 0 = fp32
}

// ---------------- prep1: transposes / scaled copies + P/pp2 presets ----------------
__global__ __launch_bounds__(256) void k_prep1(const void* q, const void* Wcq, const void* Wca,
      const void* Wwc, const void* Wrm, const void* Wrc, const void* Wra,
      const void* bp, const void* bcq,
      float* qT, float* W1f, float* Wwcf, float* WrmTf, float* W2f,
      float* P, float* pp2, const int* flag){
  const int isbf = *flag;
  __shared__ float lds[32][33];
  int bk = blockIdx.x, tid = threadIdx.x;
  int tx = tid & 31, ty = tid >> 5;
  if (bk >= 1280){                       // pp2 preset = bcq[j]*Wca[j]
    int l = bk - 1280;
    for (int idx = l*256 + tid; idx < 786432; idx += 64*256){
      int j = (idx >> 7) & 511;
      pp2[idx] = LDX(bcq, j, isbf) * LDX(Wca, j, isbf);
    }
    return;
  }
  if (bk >= 1216){                       // P preset = bp
    int l = bk - 1216;
    for (int idx = l*256 + tid; idx < 786432; idx += 64*256)
      P[idx] = LDX(bp, idx >> 7, isbf);
    return;
  }
  if (bk >= 1152){                       // W2f = Wrc * Wra
    int l = bk - 1152;
    if (isbf){
      const u16* w = (const u16*)Wrc; const u16* s = (const u16*)Wra;
      for (int idx = l*256 + tid; idx < 524288; idx += 64*256)
        W2f[idx] = bf2f(w[idx]) * bf2f(s[idx >> 10]);
    } else {
      const float* w = (const float*)Wrc; const float* s = (const float*)Wra;
      for (int idx = l*256 + tid; idx < 524288; idx += 64*256)
        W2f[idx] = w[idx] * s[idx >> 10];
    }
    return;
  }
  const void* in = nullptr; const void* scale = nullptr; float* out = nullptr;
  int ld = 0, R = 0, tR = 0, tC = 0;
  if (bk < 128)      { in = q;   ld = 1024; R = 128; out = qT;    tR = bk & 3;  tC = bk >> 2; }
  else if (bk < 384) { int l = bk - 128; in = Wcq; ld = 1024; R = 512; out = W1f;  scale = Wca; tR = l & 15; tC = l >> 4; }
  else if (bk < 896) { int l = bk - 384; in = Wwc; ld = 1024; R = 512; out = Wwcf; tR = l & 15; tC = l >> 4; }
  else               { int l = bk - 896; in = Wrm; ld = 512;  R = 512; out = WrmTf;tR = l & 15; tC = l >> 4; }
  int r0 = tR*32, c0 = tC*32;
  #pragma unroll
  for (int kk = 0; kk < 4; kk++){
    int r = r0 + ty + kk*8;
    float v = LDX(in, (size_t)r*ld + c0 + tx, isbf);
    if (scale) v *= LDX(scale, r, isbf);
    lds[tx][ty + kk*8] = v;
  }
  __syncthreads();
  #pragma unroll
  for (int kk = 0; kk < 4; kk++){
    int oc = ty + kk*8;
    out[(size_t)(c0 + oc)*R + r0 + tx] = lds[oc][tx];
  }
}

// ---------------- K_P: K-split x4, atomic into bp-preset P ----------------
__global__ __launch_bounds__(512) void k_P(const float* qT, const void* Wp,
                                           float* P, const int* flag){
  const int isbf = *flag;
  int bk = blockIdx.x;                      // 1536 = 12t * 32et * 4kc
  int t = bk >> 7; int r = bk & 127; int et = r >> 2; int kc = r & 3;
  int tid = threadIdx.x;
  int b = tid & 127;
  int ih = __builtin_amdgcn_readfirstlane(tid >> 7);
  int e0 = et*16 + ih*4;
  float acc[4] = {0.f, 0.f, 0.f, 0.f};
  size_t wo = (size_t)(t*D + e0)*D2;
  int x0 = kc*256;
  if (isbf){
    const u16* wb = (const u16*)Wp + wo;
    for (int x = x0; x < x0 + 256; x += 8){
      float a[8];
      #pragma unroll
      for (int u = 0; u < 8; u++) a[u] = qT[(x+u)*BB + b];
      #pragma unroll
      for (int kk = 0; kk < 4; kk++){
        ushort4 w0 = *(const ushort4*)(wb + kk*D2 + x);
        ushort4 w1 = *(const ushort4*)(wb + kk*D2 + x + 4);
        acc[kk] += a[0]*bf2f(w0.x) + a[1]*bf2f(w0.y) + a[2]*bf2f(w0.z) + a[3]*bf2f(w0.w)
                 + a[4]*bf2f(w1.x) + a[5]*bf2f(w1.y) + a[6]*bf2f(w1.z) + a[7]*bf2f(w1.w);
      }
    }
  } else {
    const float* wb = (const float*)Wp + wo;
    for (int x = x0; x < x0 + 256; x += 8){
      float a[8];
      #pragma unroll
      for (int u = 0; u < 8; u++) a[u] = qT[(x+u)*BB + b];
      #pragma unroll
      for (int kk = 0; kk < 4; kk++){
        float4 w0 = *(const float4*)(wb + kk*D2 + x);
        float4 w1 = *(const float4*)(wb + kk*D2 + x + 4);
        acc[kk] += a[0]*w0.x + a[1]*w0.y + a[2]*w0.z + a[3]*w0.w
                 + a[4]*w1.x + a[5]*w1.y + a[6]*w1.z + a[7]*w1.w;
      }
    }
  }
  #pragma unroll
  for (int kk = 0; kk < 4; kk++)
    atomicAdd(&P[(size_t)(t*D + e0 + kk)*BB + b], acc[kk]);
}

// ---------------- K_pp2: K-split x2, atomic into (bcq*Wca)-preset pp2 ----------------
__global__ __launch_bounds__(512) void k_pp2(const float* P, const void* Wcq,
                                             const void* Wca, float* pp2, const int* flag){
  const int isbf = *flag;
  int bk = blockIdx.x;                      // 768 = 12t * 32jt * 2kc
  int t = bk >> 6; int r = bk & 63; int jt = r >> 1; int kc = r & 1;
  int tid = threadIdx.x;
  int b = tid & 127;
  int ih = __builtin_amdgcn_readfirstlane(tid >> 7);
  int j0 = jt*16 + ih*4;
  float acc[4] = {0.f, 0.f, 0.f, 0.f};
  int e0k = kc*256;
  if (isbf){
    const u16* w = (const u16*)Wcq;
    for (int e = e0k; e < e0k + 256; e += 8){
      float a[8];
      #pragma unroll
      for (int u = 0; u < 8; u++) a[u] = P[(size_t)(t*D + e + u)*BB + b];
      #pragma unroll
      for (int kk = 0; kk < 4; kk++){
        ushort4 w0 = *(const ushort4*)(w + (size_t)(j0+kk)*D2 + D + e);
        ushort4 w1 = *(const ushort4*)(w + (size_t)(j0+kk)*D2 + D + e + 4);
        acc[kk] += a[0]*bf2f(w0.x) + a[1]*bf2f(w0.y) + a[2]*bf2f(w0.z) + a[3]*bf2f(w0.w)
                 + a[4]*bf2f(w1.x) + a[5]*bf2f(w1.y) + a[6]*bf2f(w1.z) + a[7]*bf2f(w1.w);
      }
    }
  } else {
    const float* w = (const float*)Wcq;
    for (int e = e0k; e < e0k + 256; e += 8){
      float a[8];
      #pragma unroll
      for (int u = 0; u < 8; u++) a[u] = P[(size_t)(t*D + e + u)*BB + b];
      #pragma unroll
      for (int kk = 0; kk < 4; kk++){
        float4 w0 = *(const float4*)(w + (size_t)(j0+kk)*D2 + D + e);
        float4 w1 = *(const float4*)(w + (size_t)(j0+kk)*D2 + D + e + 4);
        acc[kk] += a[0]*w0.x + a[1]*w0.y + a[2]*w0.z + a[3]*w0.w
                 + a[4]*w1.x + a[5]*w1.y + a[6]*w1.z + a[7]*w1.w;
      }
    }
  }
  #pragma unroll
  for (int kk = 0; kk < 4; kk++)
    atomicAdd(&pp2[(size_t)(t*D + j0 + kk)*BB + b], acc[kk] * LDX(Wca, j0 + kk, isbf));
}

// ---------------- K_initA ----------------
__global__ __launch_bounds__(256) void k_initA(const void* ctrl0, const void* mem0,
                                               const void* Wcq, const void* Wca,
                                               const void* Wrm, const void* brm,
                                               float* ubase, float* mmb, const int* flag){
  const int isbf = *flag;
  int bk = blockIdx.x, tid = threadIdx.x;
  int lane = tid & 63, w = tid >> 6;
  int grp = lane >> 3, k = lane & 7;
  int isU = (bk < 16);
  int o = (isU ? bk : bk - 16)*32 + w*8 + grp;
  const void* vec = isU ? ctrl0 : mem0;
  const void* mat = isU ? Wcq : Wrm;
  int ld = isU ? D2 : D;
  float acc = 0.f;
  #pragma unroll 4
  for (int it = 0; it < 16; it++){
    int d = it*32 + k*4;
    float4 v = LD4(vec, d, isbf);
    float4 m = LD4(mat, (size_t)o*ld + d, isbf);
    acc += v.x*m.x + v.y*m.y + v.z*m.z + v.w*m.w;
  }
  acc += __shfl_xor(acc, 1, 64);
  acc += __shfl_xor(acc, 2, 64);
  acc += __shfl_xor(acc, 4, 64);
  if (k == 0){
    if (isU) ubase[o] = acc * LDX(Wca, o, isbf);
    else     mmb[o]   = acc + LDX(brm, o, isbf);
  }
}

// ---------------- K_initB: u0, mm0, m_{-1}, zero wbuf (wbuf only for fallback path) ----------------
__global__ __launch_bounds__(256) void k_initB(const float* ubase, const float* mmb,
                                               const void* mem0, const float* pp2,
                                               float* u0, float* mm0, float* act0, float* wbuf,
                                               const int* flag){
  const int isbf = *flag;
  for (int idx = blockIdx.x*256 + threadIdx.x; idx < 3*D*BB + D2*BB; idx += 160*256){
    if (idx < D*BB)            u0[idx] = ubase[idx >> 7] + pp2[idx];
    else if (idx < 2*D*BB)   { int x = idx - D*BB;   mm0[x] = mmb[x >> 7]; }
    else if (idx < 3*D*BB)   { int x = idx - 2*D*BB; act0[D*BB + x] = LDX(mem0, x >> 7, isbf); }
    else                       wbuf[idx - 3*D*BB] = 0.f;
  }
}

// ================ shared attention bodies ================
__device__ void attn1_body(const void* ctx, const float* u_cur, float* cbuf,
                           int b, int tid, int isbf, float* sm){
  float* cch = sm;            // [16][512]
  float* lg  = sm + 8192;     // [16]
  int lane = tid & 63, wv = tid >> 6;
  float ur[8];
  #pragma unroll
  for (int kk = 0; kk < 4; kk++){
    ur[kk]   = u_cur[(lane*4 + kk)*BB + b];
    ur[4+kk] = u_cur[(256 + lane*4 + kk)*BB + b];
  }
  float mv = -INFINITY, ls = 0.f, o = 0.f;     // thread owns d = tid
  for (int c = 0; c < 8; c++){
    int s0 = c*16;
    #pragma unroll
    for (int rr = 0; rr < 2; rr++){
      int loc = rr*8 + wv;
      int s = s0 + loc;
      float4 c0, c1;
      if (isbf){
        const u16* crow = (const u16*)ctx + ((size_t)(b*SS + s))*D;
        ushort4 h0 = *(const ushort4*)(crow + lane*4);
        ushort4 h1 = *(const ushort4*)(crow + 256 + lane*4);
        c0 = make_float4(bf2f(h0.x), bf2f(h0.y), bf2f(h0.z), bf2f(h0.w));
        c1 = make_float4(bf2f(h1.x), bf2f(h1.y), bf2f(h1.z), bf2f(h1.w));
      } else {
        const float* crow = (const float*)ctx + ((size_t)(b*SS + s))*D;
        c0 = *(const float4*)(crow + lane*4);
        c1 = *(const float4*)(crow + 256 + lane*4);
      }
      *(float4*)&cch[loc*512 + lane*4]       = c0;
      *(float4*)&cch[loc*512 + 256 + lane*4] = c1;
      float dot = ur[0]*c0.x + ur[1]*c0.y + ur[2]*c0.z + ur[3]*c0.w
                + ur[4]*c1.x + ur[5]*c1.y + ur[6]*c1.z + ur[7]*c1.w;
      #pragma unroll
      for (int off = 32; off; off >>= 1) dot += __shfl_down(dot, off, 64);
      if (lane == 0) lg[loc] = dot;
    }
    __syncthreads();
    float Mc = lg[0];
    #pragma unroll
    for (int s = 1; s < 16; s++) Mc = fmaxf(Mc, lg[s]);
    float mn = fmaxf(mv, Mc);
    float sc = __expf(mv - mn);
    ls *= sc; o *= sc;
    #pragma unroll
    for (int s = 0; s < 16; s++){
      float e = __expf(lg[s] - mn);
      ls += e;
      o += e * cch[s*512 + tid];
    }
    mv = mn;
    __syncthreads();
  }
  cbuf[tid*BB + b] = o / ls;
}

__device__ void attn2_body(const void* kmat, const float* wbuf, const float* mm_cur,
                           float* act_cur, int b, int tid, int isbf, float* sm){
  float* u2 = sm;           // 512
  float* lg = sm + 512;     // 256
  float* red= sm + 768;     // 256
  float* ps = sm + 1024;    // 2 x 256
  u2[tid] = wbuf[tid*BB + b]*mm_cur[tid*BB + b] + wbuf[(D + tid)*BB + b];
  __syncthreads();
  {
    int half = tid >> 8;
    int n = tid & 255;
    float part = 0.f;
    if (n < NN){
      float c[8];
      #pragma unroll
      for (int u = 0; u < 8; u++) c[u] = 0.f;
      int d0 = half*256;
      if (isbf){
        const u16* kb = (const u16*)kmat + (size_t)b*D*NN + n;
        for (int dd = 0; dd < 256; dd += 8){
          #pragma unroll
          for (int u = 0; u < 8; u++) c[u] += u2[d0+dd+u]*bf2f(kb[(size_t)(d0+dd+u)*NN]);
        }
      } else {
        const float* kb = (const float*)kmat + (size_t)b*D*NN + n;
        for (int dd = 0; dd < 256; dd += 8){
          #pragma unroll
          for (int u = 0; u < 8; u++) c[u] += u2[d0+dd+u]*kb[(size_t)(d0+dd+u)*NN];
        }
      }
      part = (((c[0]+c[1]) + (c[2]+c[3])) + ((c[4]+c[5]) + (c[6]+c[7])));
    }
    ps[half*256 + n] = part;
  }
  __syncthreads();
  if (tid < 256){
    float logit = (tid < NN) ? (ps[tid] + ps[256 + tid]) : -INFINITY;
    lg[tid] = logit; red[tid] = logit;
  }
  __syncthreads();
  for (int off = 128; off; off >>= 1){ if (tid < off) red[tid] = fmaxf(red[tid], red[tid+off]); __syncthreads(); }
  float M = red[0];
  __syncthreads();
  if (tid < 256){ float e = (tid < NN) ? __expf(lg[tid] - M) : 0.f; lg[tid] = e; red[tid] = e; }
  __syncthreads();
  for (int off = 128; off; off >>= 1){ if (tid < off) red[tid] += red[tid+off]; __syncthreads(); }
  float inv = 1.f / red[0];
  int lane = tid & 63, wv = tid >> 6;
  for (int i = 0; i < 32; i++){
    int dA = wv + i*16, dB = dA + 8;
    float p, qv;
    if (isbf){
      const u16* krA = (const u16*)kmat + (size_t)b*D*NN + (size_t)dA*NN;
      const u16* krB = (const u16*)kmat + (size_t)b*D*NN + (size_t)dB*NN;
      p  = lg[lane]*bf2f(krA[lane]) + lg[lane+64]*bf2f(krA[lane+64]) + lg[lane+128]*bf2f(krA[lane+128]);
      qv = lg[lane]*bf2f(krB[lane]) + lg[lane+64]*bf2f(krB[lane+64]) + lg[lane+128]*bf2f(krB[lane+128]);
      if (lane < NN - 192){
        p  += lg[lane+192]*bf2f(krA[lane+192]);
        qv += lg[lane+192]*bf2f(krB[lane+192]);
      }
    } else {
      const float* krA = (const float*)kmat + (size_t)b*D*NN + (size_t)dA*NN;
      const float* krB = (const float*)kmat + (size_t)b*D*NN + (size_t)dB*NN;
      p  = lg[lane]*krA[lane] + lg[lane+64]*krA[lane+64] + lg[lane+128]*krA[lane+128];
      qv = lg[lane]*krB[lane] + lg[lane+64]*krB[lane+64] + lg[lane+128]*krB[lane+128];
      if (lane < NN - 192){
        p  += lg[lane+192]*krA[lane+192];
        qv += lg[lane+192]*krB[lane+192];
      }
    }
    #pragma unroll
    for (int off = 32; off; off >>= 1){
      p  += __shfl_down(p , off, 64);
      qv += __shfl_down(qv, off, 64);
    }
    if (lane == 0){
      act_cur[dA*BB + b] = p  * inv;
      act_cur[dB*BB + b] = qv * inv;
    }
  }
}

// ================ FUSED 12-step cooperative kernel ================
// 256 blocks x 512 threads. Exclusive-output gemvs: no atomics, no presets.
__global__ __launch_bounds__(512) void k_steps(const void* ctx, const void* kmat,
      const void* brm, const void* bwc,
      float* ubuf, float* cbuf, float* wbuf, float* mmbuf, float* actb,
      const float* pp2, const float* W2f, const float* Wwcf, const float* W1f,
      const float* WrmTf, const int* flag){
  cg::grid_group grid = cg::this_grid();
  const int isbf = *flag;
  int bk = blockIdx.x, tid = threadIdx.x;
  int b = tid & 127;
  int ih = tid >> 7;                       // 0..3
  __shared__ float sm[8208];
  for (int t = 0; t < TT; t++){
    int cur = t & 1, nxt = cur ^ 1;
    const float* u_cur = ubuf + cur*65536;
    float* u_nxt = ubuf + nxt*65536;
    float* mm_cur = mmbuf + cur*65536;
    float* act_cur = actb + cur*131072;
    float* act_nxt = actb + nxt*131072;
    // ---- phase 1: ctx attention (bk<128) + mm gemv (bk>=128, t>0) ----
    if (bk < BB){
      attn1_body(ctx, u_cur, cbuf, bk, tid, isbf, sm);
    } else if (t > 0){
      int i = (bk - BB)*4 + ih;
      float acc = LDX(brm, i, isbf);
      for (int d = 0; d < D; d += 8){
        float av[8];
        #pragma unroll
        for (int u = 0; u < 8; u++) av[u] = act_cur[(size_t)(D + d + u)*BB + b];
        #pragma unroll
        for (int u = 0; u < 8; u++) acc += av[u] * WrmTf[(size_t)(d+u)*D + i];
      }
      mm_cur[(size_t)i*BB + b] = acc;
    }
    grid.sync();
    // ---- phase 2: wbuf[e] = sum_j cbuf[j] * W2f[j,e]  (exclusive e) ----
    {
      int e = bk*4 + ih;
      float acc = 0.f;
      for (int j = 0; j < D; j += 8){
        float av[8];
        #pragma unroll
        for (int u = 0; u < 8; u++) av[u] = cbuf[(j+u)*BB + b];
        #pragma unroll
        for (int u = 0; u < 8; u++) acc += av[u] * W2f[(size_t)(j+u)*D2 + e];
      }
      wbuf[(size_t)e*BB + b] = acc;
    }
    grid.sync();
    // ---- phase 3: k attention -> r into act_cur rows 0..D ----
    if (bk < BB){
      attn2_body(kmat, wbuf, mm_cur, act_cur, bk, tid, isbf, sm);
    }
    grid.sync();
    // ---- phase 4: m = bwc + Wwc^T [r; m_prev]  and  u_next = pp2 + W1f^T c ----
    if (bk < BB){
      int i = bk*4 + ih;
      float acc = LDX(bwc, i, isbf);
      for (int e = 0; e < D2; e += 8){
        float av[8];
        #pragma unroll
        for (int u = 0; u < 8; u++) av[u] = act_cur[(size_t)(e+u)*BB + b];
        #pragma unroll
        for (int u = 0; u < 8; u++) acc += av[u] * Wwcf[(size_t)(e+u)*D + i];
      }
      act_nxt[(size_t)(D + i)*BB + b] = acc;
    } else if (t < TT-1){
      int j = (bk - BB)*4 + ih;
      float acc = 0.f;
      for (int e = 0; e < D; e += 8){
        float av[8];
        #pragma unroll
        for (int u = 0; u < 8; u++) av[u] = cbuf[(e+u)*BB + b];
        #pragma unroll
        for (int u = 0; u < 8; u++) acc += av[u] * W1f[(size_t)(e+u)*D + j];
      }
      u_nxt[(size_t)j*BB + b] = pp2[(size_t)((t+1)*D + j)*BB + b] + acc;
    }
    grid.sync();
  }
}

// ================ fallback per-step kernels (round-7 semantics) ================
__global__ __launch_bounds__(512) void k_A1(const void* ctx, const float* ubuf, float* cbuf,
                                            const float* act_cur, float* mm_cur,
                                            const float* WrmTf, int t, const int* flag){
  __shared__ float sm[8208];
  int bk = blockIdx.x, tid = threadIdx.x;
  if (bk >= BB){
    if (t == 0) return;
    int l = bk - BB;
    int b = tid & 127;
    int ih = (tid >> 7) & 3;
    int it = l >> 2, kc = l & 3;
    int i0 = it*32 + ih*8;
    float acc[8] = {0.f,0.f,0.f,0.f,0.f,0.f,0.f,0.f};
    int d0 = kc*128;
    for (int d = d0; d < d0 + 128; d += 8){
      float av[8];
      #pragma unroll
      for (int u = 0; u < 8; u++) av[u] = act_cur[(size_t)(D + d + u)*BB + b];
      #pragma unroll
      for (int u = 0; u < 8; u++){
        float4 w0 = *(const float4*)(WrmTf + (size_t)(d+u)*D + i0);
        float4 w1 = *(const float4*)(WrmTf + (size_t)(d+u)*D + i0 + 4);
        acc[0]+=av[u]*w0.x; acc[1]+=av[u]*w0.y; acc[2]+=av[u]*w0.z; acc[3]+=av[u]*w0.w;
        acc[4]+=av[u]*w1.x; acc[5]+=av[u]*w1.y; acc[6]+=av[u]*w1.z; acc[7]+=av[u]*w1.w;
      }
    }
    #pragma unroll
    for (int kk = 0; kk < 8; kk++) atomicAdd(&mm_cur[(size_t)(i0 + kk)*BB + b], acc[kk]);
    return;
  }
  attn1_body(ctx, ubuf, cbuf, bk, tid, *flag, sm);
}

__global__ __launch_bounds__(256) void k_G2(const float* cbuf, const float* W2f, float* wbuf,
                                            const float* pp2_next, float* u_nxt,
                                            const void* brm, float* mm_nxt,
                                            const void* bwc, float* act_nxt, int t, const int* flag){
  int bk = blockIdx.x, tid = threadIdx.x;
  if (bk < 512){
    int et = bk >> 2, kc = bk & 3;
    int b = tid & 127;
    int ih = __builtin_amdgcn_readfirstlane(tid >> 7);
    int e0 = et*8 + ih*4;
    float acc[4] = {0.f, 0.f, 0.f, 0.f};
    int j0 = kc*128;
    for (int j = j0; j < j0 + 128; j += 8){
      float av[8];
      #pragma unroll
      for (int u = 0; u < 8; u++) av[u] = cbuf[(j+u)*BB + b];
      #pragma unroll
      for (int u = 0; u < 8; u++){
        float4 wv = *(const float4*)(W2f + (size_t)(j+u)*D2 + e0);
        acc[0] += av[u]*wv.x; acc[1] += av[u]*wv.y;
        acc[2] += av[u]*wv.z; acc[3] += av[u]*wv.w;
      }
    }
    #pragma unroll
    for (int kk = 0; kk < 4; kk++) atomicAdd(&wbuf[(e0+kk)*BB + b], acc[kk]);
  } else if (bk < 528){
    if (t < TT-1)
      for (int x = (bk-512)*256 + tid; x < D*BB; x += 16*256) u_nxt[x] = pp2_next[x];
  } else if (bk < 544){
    if (t < TT-1){
      const int isbf = *flag;
      for (int x = (bk-528)*256 + tid; x < D*BB; x += 16*256)
        mm_nxt[x] = LDX(brm, x >> 7, isbf);
    }
  } else {
    const int isbf = *flag;
    for (int x = (bk-544)*256 + tid; x < D*BB; x += 16*256)
      act_nxt[D*BB + x] = LDX(bwc, x >> 7, isbf);
  }
}

__global__ __launch_bounds__(512) void k_A2(const void* kmat, const float* wbuf,
                                            const float* mmbuf, float* act_cur, const int* flag){
  __shared__ float sm[1536];
  attn2_body(kmat, wbuf, mmbuf, act_cur, blockIdx.x, threadIdx.x, *flag, sm);
}

__global__ __launch_bounds__(256) void k_G3(const float* act_cur, const float* cbuf,
                                            const float* Wwcf, const float* W1f,
                                            float* act_nxt, float* u_nxt, float* wbuf,
                                            int t){
  int bk = blockIdx.x, tid = threadIdx.x;
  int b = tid & 127;
  int ih = __builtin_amdgcn_readfirstlane(tid >> 7);
  if (bk < 256){
    int it = bk >> 3, kc = bk & 7;
    int i0 = it*16 + ih*8;
    float acc[8] = {0.f,0.f,0.f,0.f,0.f,0.f,0.f,0.f};
    int e0 = kc*128;
    for (int e = e0; e < e0 + 128; e += 8){
      float av[8];
      #pragma unroll
      for (int u = 0; u < 8; u++) av[u] = act_cur[(e+u)*BB + b];
      #pragma unroll
      for (int u = 0; u < 8; u++){
        float4 w0 = *(const float4*)(Wwcf + (size_t)(e+u)*D + i0);
        float4 w1 = *(const float4*)(Wwcf + (size_t)(e+u)*D + i0 + 4);
        acc[0]+=av[u]*w0.x; acc[1]+=av[u]*w0.y; acc[2]+=av[u]*w0.z; acc[3]+=av[u]*w0.w;
        acc[4]+=av[u]*w1.x; acc[5]+=av[u]*w1.y; acc[6]+=av[u]*w1.z; acc[7]+=av[u]*w1.w;
      }
    }
    #pragma unroll
    for (int kk = 0; kk < 8; kk++) atomicAdd(&act_nxt[(size_t)(D + i0 + kk)*BB + b], acc[kk]);
  } else if (bk < 384){
    if (t == TT-1) return;
    int l = bk - 256;
    int it = l >> 2, kc = l & 3;
    int j0 = it*16 + ih*8;
    float acc[8] = {0.f,0.f,0.f,0.f,0.f,0.f,0.f,0.f};
    int e0 = kc*128;
    for (int e = e0; e < e0 + 128; e += 8){
      float av[8];
      #pragma unroll
      for (int u = 0; u < 8; u++) av[u] = cbuf[(e+u)*BB + b];
      #pragma unroll
      for (int u = 0; u < 8; u++){
        float4 w0 = *(const float4*)(W1f + (size_t)(e+u)*D + j0);
        float4 w1 = *(const float4*)(W1f + (size_t)(e+u)*D + j0 + 4);
        acc[0]+=av[u]*w0.x; acc[1]+=av[u]*w0.y; acc[2]+=av[u]*w0.z; acc[3]+=av[u]*w0.w;
        acc[4]+=av[u]*w1.x; acc[5]+=av[u]*w1.y; acc[6]+=av[u]*w1.z; acc[7]+=av[u]*w1.w;
      }
    }
    #pragma unroll
    for (int kk = 0; kk < 8; kk++) atomicAdd(&u_nxt[(j0 + kk)*BB + b], acc[kk]);
  } else {
    if (t == TT-1) return;
    for (int x = (bk-384)*256 + tid; x < D2*BB; x += 16*256) wbuf[x] = 0.f;
  }
}

// ---------------- K_out ----------------
__global__ __launch_bounds__(256) void k_out(const float* act_fin, void* out, const int* flag){
  const int isbf = *flag;
  __shared__ float lds[32][33];
  int bk = blockIdx.x;
  int it = bk >> 2, bt = bk & 3;
  int tx = threadIdx.x & 31, ty = threadIdx.x >> 5;
  #pragma unroll
  for (int kk = 0; kk < 4; kk++){
    int i = it*32 + ty + kk*8;
    lds[tx][ty + kk*8] = act_fin[(D + i)*BB + bt*32 + tx];
  }
  __syncthreads();
  if (isbf){
    __hip_bfloat16* o = (__hip_bfloat16*)out;
    #pragma unroll
    for (int kk = 0; kk < 4; kk++){
      int bb = bt*32 + ty + kk*8;
      o[(size_t)bb*D + it*32 + tx] = __float2bfloat16(lds[ty + kk*8][tx]);
    }
  } else {
    float* o = (float*)out;
    #pragma unroll
    for (int kk = 0; kk < 4; kk++){
      int bb = bt*32 + ty + kk*8;
      o[(size_t)bb*D + it*32 + tx] = lds[ty + kk*8][tx];
    }
  }
}

extern "C" void kernel_launch(void* const* d_in, const int* in_sizes, int n_in,
                              void* d_out, int out_size, void* d_ws, size_t ws_size,
                              hipStream_t stream){
  const void* ctx  = d_in[0];
  const void* q    = d_in[1];
  const void* kmat = d_in[2];
  const void* mem0 = d_in[3];
  const void* ctrl0= d_in[4];
  const void* Wp   = d_in[5];
  const void* bp   = d_in[6];
  const void* Wcq  = d_in[7];
  const void* bcq  = d_in[8];
  const void* Wca  = d_in[9];
  const void* Wrm  = d_in[11];
  const void* brm  = d_in[12];
  const void* Wrc  = d_in[13];
  const void* Wra  = d_in[15];
  const void* Wwc  = d_in[17];
  const void* bwc  = d_in[18];

  float* W      = (float*)d_ws;
  float* qT     = W;
  float* P      = W + 131072;
  float* pp2    = W + 917504;
  float* W1f    = W + 1703936;
  float* W2f    = W + 1966080;
  float* Wwcf   = W + 2490368;
  float* WrmTf  = W + 3014656;
  float* ubuf   = W + 3801600;   // 2 x 65536
  float* cbuf   = W + 3932672;
  float* wbuf   = W + 3998208;
  float* mmbuf  = W + 4129280;   // 2 x 65536
  float* actb   = W + 4260352;   // 2 x 131072
  int*   flag   = (int*)(W + 4522496);
  float* ubase  = W + 4522560;
  float* mmb    = W + 4523072;

  hipLaunchKernelGGL(k_detect, dim3(1), dim3(256), 0, stream, (const u16*)ctx, flag);
  hipLaunchKernelGGL(k_prep1, dim3(1344), dim3(256), 0, stream,
                     q, Wcq, Wca, Wwc, Wrm, Wrc, Wra, bp, bcq,
                     qT, W1f, Wwcf, WrmTf, W2f, P, pp2, flag);
  hipLaunchKernelGGL(k_P,    dim3(1536), dim3(512), 0, stream, qT, Wp, P, flag);
  hipLaunchKernelGGL(k_pp2,  dim3(768), dim3(512), 0, stream, P, Wcq, Wca, pp2, flag);
  hipLaunchKernelGGL(k_initA, dim3(32), dim3(256), 0, stream,
                     ctrl0, mem0, Wcq, Wca, Wrm, brm, ubase, mmb, flag);
  hipLaunchKernelGGL(k_initB, dim3(160), dim3(256), 0, stream,
                     ubase, mmb, mem0, pp2, ubuf, mmbuf, actb, wbuf, flag);

  void* kargs[] = { (void*)&ctx, (void*)&kmat, (void*)&brm, (void*)&bwc,
                    (void*)&ubuf, (void*)&cbuf, (void*)&wbuf, (void*)&mmbuf, (void*)&actb,
                    (void*)&pp2, (void*)&W2f, (void*)&Wwcf, (void*)&W1f,
                    (void*)&WrmTf, (void*)&flag };
  hipError_t ce = hipLaunchCooperativeKernel((void*)k_steps, dim3(256), dim3(512),
                                             kargs, 0, stream);
  if (ce != hipSuccess){
    (void)hipGetLastError();
    for (int t = 0; t < TT; t++){
      int cur = t & 1, nxt = 1 - cur;
      hipLaunchKernelGGL(k_A1, dim3(192), dim3(512), 0, stream,
                         ctx, ubuf + cur*65536, cbuf,
                         actb + cur*131072, mmbuf + cur*65536, WrmTf, t, flag);
      hipLaunchKernelGGL(k_G2, dim3(560), dim3(256), 0, stream,
                         cbuf, W2f, wbuf,
                         pp2 + ((t+1 < TT) ? (t+1)*65536 : 0), ubuf + nxt*65536,
                         brm, mmbuf + nxt*65536,
                         bwc, actb + nxt*131072, t, flag);
      hipLaunchKernelGGL(k_A2, dim3(128), dim3(512), 0, stream,
                         kmat, wbuf, mmbuf + cur*65536, actb + cur*131072, flag);
      hipLaunchKernelGGL(k_G3, dim3(400), dim3(256), 0, stream,
                         actb + cur*131072, cbuf, Wwcf, W1f,
                         actb + nxt*131072, ubuf + nxt*65536, wbuf, t);
    }
  }
  hipLaunchKernelGGL(k_out, dim3(64), dim3(256), 0, stream, actb, d_out, flag);
}

// Round 9
// 1571.318 us; speedup vs baseline: 2.1790x; 2.1790x over previous
//
#include <hip/hip_runtime.h>
#include <hip/hip_bf16.h>
#include <cstdint>

#define D  512
#define D2 1024
#define BB 128
#define SS 128
#define NN 196
#define TT 12

typedef unsigned short u16;

__device__ __forceinline__ float bf2f(u16 h){
  union { unsigned int u; float f; } v; v.u = ((unsigned int)h) << 16; return v.f;
}

__device__ __forceinline__ float LDX(const void* p, size_t i, int isbf){
  if (isbf) return bf2f(((const u16*)p)[i]);
  return ((const float*)p)[i];
}

__device__ __forceinline__ float4 LD4(const void* p, size_t i, int isbf){
  if (isbf){
    ushort4 w = *(const ushort4*)((const u16*)p + i);
    return make_float4(bf2f(w.x), bf2f(w.y), bf2f(w.z), bf2f(w.w));
  }
  return *(const float4*)((const float*)p + i);
}

// ---------------- detect input dtype ----------------
__global__ __launch_bounds__(256) void k_detect(const u16* ctx, int* flag){
  __shared__ int cnt;
  if (threadIdx.x == 0) cnt = 0;
  __syncthreads();
  int bad = 0;
  for (int i = threadIdx.x; i < 8192; i += 256){
    int e = (ctx[i] >> 7) & 0xFF;
    if (e == 0xFF || (e != 0 && (e < 90 || e > 160))) bad++;
  }
  atomicAdd(&cnt, bad);
  __syncthreads();
  if (threadIdx.x == 0) *flag = (cnt > 100) ? 0 : 1;   // 1 = bf16, 0 = fp32
}

// ---------------- prep1: transposes / scaled copies + P/pp2 presets ----------------
__global__ __launch_bounds__(256) void k_prep1(const void* q, const void* Wcq, const void* Wca,
      const void* Wwc, const void* Wrm, const void* Wrc, const void* Wra,
      const void* bp, const void* bcq,
      float* qT, float* W1f, float* Wwcf, float* WrmTf, float* W2f,
      float* P, float* pp2, const int* flag){
  const int isbf = *flag;
  __shared__ float lds[32][33];
  int bk = blockIdx.x, tid = threadIdx.x;
  int tx = tid & 31, ty = tid >> 5;
  if (bk >= 1280){                       // pp2 preset = bcq[j]*Wca[j]
    int l = bk - 1280;
    for (int idx = l*256 + tid; idx < 786432; idx += 64*256){
      int j = (idx >> 7) & 511;
      pp2[idx] = LDX(bcq, j, isbf) * LDX(Wca, j, isbf);
    }
    return;
  }
  if (bk >= 1216){                       // P preset = bp
    int l = bk - 1216;
    for (int idx = l*256 + tid; idx < 786432; idx += 64*256)
      P[idx] = LDX(bp, idx >> 7, isbf);
    return;
  }
  if (bk >= 1152){                       // W2f = Wrc * Wra
    int l = bk - 1152;
    if (isbf){
      const u16* w = (const u16*)Wrc; const u16* s = (const u16*)Wra;
      for (int idx = l*256 + tid; idx < 524288; idx += 64*256)
        W2f[idx] = bf2f(w[idx]) * bf2f(s[idx >> 10]);
    } else {
      const float* w = (const float*)Wrc; const float* s = (const float*)Wra;
      for (int idx = l*256 + tid; idx < 524288; idx += 64*256)
        W2f[idx] = w[idx] * s[idx >> 10];
    }
    return;
  }
  const void* in = nullptr; const void* scale = nullptr; float* out = nullptr;
  int ld = 0, R = 0, tR = 0, tC = 0;
  if (bk < 128)      { in = q;   ld = 1024; R = 128; out = qT;    tR = bk & 3;  tC = bk >> 2; }
  else if (bk < 384) { int l = bk - 128; in = Wcq; ld = 1024; R = 512; out = W1f;  scale = Wca; tR = l & 15; tC = l >> 4; }
  else if (bk < 896) { int l = bk - 384; in = Wwc; ld = 1024; R = 512; out = Wwcf; tR = l & 15; tC = l >> 4; }
  else               { int l = bk - 896; in = Wrm; ld = 512;  R = 512; out = WrmTf;tR = l & 15; tC = l >> 4; }
  int r0 = tR*32, c0 = tC*32;
  #pragma unroll
  for (int kk = 0; kk < 4; kk++){
    int r = r0 + ty + kk*8;
    float v = LDX(in, (size_t)r*ld + c0 + tx, isbf);
    if (scale) v *= LDX(scale, r, isbf);
    lds[tx][ty + kk*8] = v;
  }
  __syncthreads();
  #pragma unroll
  for (int kk = 0; kk < 4; kk++){
    int oc = ty + kk*8;
    out[(size_t)(c0 + oc)*R + r0 + tx] = lds[oc][tx];
  }
}

// ---------------- K_P: K-split x4, atomic into bp-preset P ----------------
__global__ __launch_bounds__(512) void k_P(const float* qT, const void* Wp,
                                           float* P, const int* flag){
  const int isbf = *flag;
  int bk = blockIdx.x;                      // 1536 = 12t * 32et * 4kc
  int t = bk >> 7; int r = bk & 127; int et = r >> 2; int kc = r & 3;
  int tid = threadIdx.x;
  int b = tid & 127;
  int ih = __builtin_amdgcn_readfirstlane(tid >> 7);
  int e0 = et*16 + ih*4;
  float acc[4] = {0.f, 0.f, 0.f, 0.f};
  size_t wo = (size_t)(t*D + e0)*D2;
  int x0 = kc*256;
  if (isbf){
    const u16* wb = (const u16*)Wp + wo;
    for (int x = x0; x < x0 + 256; x += 8){
      float a[8];
      #pragma unroll
      for (int u = 0; u < 8; u++) a[u] = qT[(x+u)*BB + b];
      #pragma unroll
      for (int kk = 0; kk < 4; kk++){
        ushort4 w0 = *(const ushort4*)(wb + kk*D2 + x);
        ushort4 w1 = *(const ushort4*)(wb + kk*D2 + x + 4);
        acc[kk] += a[0]*bf2f(w0.x) + a[1]*bf2f(w0.y) + a[2]*bf2f(w0.z) + a[3]*bf2f(w0.w)
                 + a[4]*bf2f(w1.x) + a[5]*bf2f(w1.y) + a[6]*bf2f(w1.z) + a[7]*bf2f(w1.w);
      }
    }
  } else {
    const float* wb = (const float*)Wp + wo;
    for (int x = x0; x < x0 + 256; x += 8){
      float a[8];
      #pragma unroll
      for (int u = 0; u < 8; u++) a[u] = qT[(x+u)*BB + b];
      #pragma unroll
      for (int kk = 0; kk < 4; kk++){
        float4 w0 = *(const float4*)(wb + kk*D2 + x);
        float4 w1 = *(const float4*)(wb + kk*D2 + x + 4);
        acc[kk] += a[0]*w0.x + a[1]*w0.y + a[2]*w0.z + a[3]*w0.w
                 + a[4]*w1.x + a[5]*w1.y + a[6]*w1.z + a[7]*w1.w;
      }
    }
  }
  #pragma unroll
  for (int kk = 0; kk < 4; kk++)
    atomicAdd(&P[(size_t)(t*D + e0 + kk)*BB + b], acc[kk]);
}

// ---------------- K_pp2: K-split x2, atomic into (bcq*Wca)-preset pp2 ----------------
__global__ __launch_bounds__(512) void k_pp2(const float* P, const void* Wcq,
                                             const void* Wca, float* pp2, const int* flag){
  const int isbf = *flag;
  int bk = blockIdx.x;                      // 768 = 12t * 32jt * 2kc
  int t = bk >> 6; int r = bk & 63; int jt = r >> 1; int kc = r & 1;
  int tid = threadIdx.x;
  int b = tid & 127;
  int ih = __builtin_amdgcn_readfirstlane(tid >> 7);
  int j0 = jt*16 + ih*4;
  float acc[4] = {0.f, 0.f, 0.f, 0.f};
  int e0k = kc*256;
  if (isbf){
    const u16* w = (const u16*)Wcq;
    for (int e = e0k; e < e0k + 256; e += 8){
      float a[8];
      #pragma unroll
      for (int u = 0; u < 8; u++) a[u] = P[(size_t)(t*D + e + u)*BB + b];
      #pragma unroll
      for (int kk = 0; kk < 4; kk++){
        ushort4 w0 = *(const ushort4*)(w + (size_t)(j0+kk)*D2 + D + e);
        ushort4 w1 = *(const ushort4*)(w + (size_t)(j0+kk)*D2 + D + e + 4);
        acc[kk] += a[0]*bf2f(w0.x) + a[1]*bf2f(w0.y) + a[2]*bf2f(w0.z) + a[3]*bf2f(w0.w)
                 + a[4]*bf2f(w1.x) + a[5]*bf2f(w1.y) + a[6]*bf2f(w1.z) + a[7]*bf2f(w1.w);
      }
    }
  } else {
    const float* w = (const float*)Wcq;
    for (int e = e0k; e < e0k + 256; e += 8){
      float a[8];
      #pragma unroll
      for (int u = 0; u < 8; u++) a[u] = P[(size_t)(t*D + e + u)*BB + b];
      #pragma unroll
      for (int kk = 0; kk < 4; kk++){
        float4 w0 = *(const float4*)(w + (size_t)(j0+kk)*D2 + D + e);
        float4 w1 = *(const float4*)(w + (size_t)(j0+kk)*D2 + D + e + 4);
        acc[kk] += a[0]*w0.x + a[1]*w0.y + a[2]*w0.z + a[3]*w0.w
                 + a[4]*w1.x + a[5]*w1.y + a[6]*w1.z + a[7]*w1.w;
      }
    }
  }
  #pragma unroll
  for (int kk = 0; kk < 4; kk++)
    atomicAdd(&pp2[(size_t)(t*D + j0 + kk)*BB + b], acc[kk] * LDX(Wca, j0 + kk, isbf));
}

// ---------------- K_initA ----------------
__global__ __launch_bounds__(256) void k_initA(const void* ctrl0, const void* mem0,
                                               const void* Wcq, const void* Wca,
                                               const void* Wrm, const void* brm,
                                               float* ubase, float* mmb, const int* flag){
  const int isbf = *flag;
  int bk = blockIdx.x, tid = threadIdx.x;
  int lane = tid & 63, w = tid >> 6;
  int grp = lane >> 3, k = lane & 7;
  int isU = (bk < 16);
  int o = (isU ? bk : bk - 16)*32 + w*8 + grp;
  const void* vec = isU ? ctrl0 : mem0;
  const void* mat = isU ? Wcq : Wrm;
  int ld = isU ? D2 : D;
  float acc = 0.f;
  #pragma unroll 4
  for (int it = 0; it < 16; it++){
    int d = it*32 + k*4;
    float4 v = LD4(vec, d, isbf);
    float4 m = LD4(mat, (size_t)o*ld + d, isbf);
    acc += v.x*m.x + v.y*m.y + v.z*m.z + v.w*m.w;
  }
  acc += __shfl_xor(acc, 1, 64);
  acc += __shfl_xor(acc, 2, 64);
  acc += __shfl_xor(acc, 4, 64);
  if (k == 0){
    if (isU) ubase[o] = acc * LDX(Wca, o, isbf);
    else     mmb[o]   = acc + LDX(brm, o, isbf);
  }
}

// ---------------- K_initB: u0, mm0, m_{-1}, zero wbuf ----------------
__global__ __launch_bounds__(256) void k_initB(const float* ubase, const float* mmb,
                                               const void* mem0, const float* pp2,
                                               float* u0, float* mm0, float* act0, float* wbuf,
                                               const int* flag){
  const int isbf = *flag;
  for (int idx = blockIdx.x*256 + threadIdx.x; idx < 3*D*BB + D2*BB; idx += 160*256){
    if (idx < D*BB)            u0[idx] = ubase[idx >> 7] + pp2[idx];
    else if (idx < 2*D*BB)   { int x = idx - D*BB;   mm0[x] = mmb[x >> 7]; }
    else if (idx < 3*D*BB)   { int x = idx - 2*D*BB; act0[D*BB + x] = LDX(mem0, x >> 7, isbf); }
    else                       wbuf[idx - 3*D*BB] = 0.f;
  }
}

// ---------------- K_A1: s-split x2 online-softmax partials + mm gemv ----------------
// bk<256: (b = bk>>1, h = bk&1) over s in [h*64, h*64+64); writes UNNORMALIZED o_h and (m_h, l_h)
// bk>=256 (t>0): mm_t += Wrm * m_{t-1}  (64 blocks, K-split x4, atomic onto brm preset)
__global__ __launch_bounds__(512) void k_A1(const void* ctx, const float* ubuf,
                                            float* obuf, float* mlbuf,
                                            const float* act_cur, float* mm_cur,
                                            const float* WrmTf, int t, const int* flag){
  int bk = blockIdx.x, tid = threadIdx.x;
  if (bk >= 256){
    if (t == 0) return;
    int l = bk - 256;                      // 0..63
    int b = tid & 127;
    int ih = (tid >> 7) & 3;
    int it = l >> 2, kc = l & 3;
    int i0 = it*32 + ih*8;
    float acc[8] = {0.f,0.f,0.f,0.f,0.f,0.f,0.f,0.f};
    int d0 = kc*128;
    for (int d = d0; d < d0 + 128; d += 8){
      float av[8];
      #pragma unroll
      for (int u = 0; u < 8; u++) av[u] = act_cur[(size_t)(D + d + u)*BB + b];
      #pragma unroll
      for (int u = 0; u < 8; u++){
        float4 w0 = *(const float4*)(WrmTf + (size_t)(d+u)*D + i0);
        float4 w1 = *(const float4*)(WrmTf + (size_t)(d+u)*D + i0 + 4);
        acc[0]+=av[u]*w0.x; acc[1]+=av[u]*w0.y; acc[2]+=av[u]*w0.z; acc[3]+=av[u]*w0.w;
        acc[4]+=av[u]*w1.x; acc[5]+=av[u]*w1.y; acc[6]+=av[u]*w1.z; acc[7]+=av[u]*w1.w;
      }
    }
    #pragma unroll
    for (int kk = 0; kk < 8; kk++) atomicAdd(&mm_cur[(size_t)(i0 + kk)*BB + b], acc[kk]);
    return;
  }
  const int isbf = *flag;
  __shared__ float cch[16][D];     // 32 KB chunk cache
  __shared__ float lg[16];
  int b = bk >> 1, h = bk & 1;
  int lane = tid & 63, wv = tid >> 6;          // 8 waves
  float ur[8];
  #pragma unroll
  for (int kk = 0; kk < 4; kk++){
    ur[kk]   = ubuf[(lane*4 + kk)*BB + b];
    ur[4+kk] = ubuf[(256 + lane*4 + kk)*BB + b];
  }
  float mv = -INFINITY, ls = 0.f, o = 0.f;     // thread owns d = tid
  for (int c = 0; c < 4; c++){
    int s0 = h*64 + c*16;
    #pragma unroll
    for (int rr = 0; rr < 2; rr++){
      int loc = rr*8 + wv;
      int s = s0 + loc;
      float4 c0, c1;
      if (isbf){
        const u16* crow = (const u16*)ctx + ((size_t)(b*SS + s))*D;
        ushort4 h0 = *(const ushort4*)(crow + lane*4);
        ushort4 h1 = *(const ushort4*)(crow + 256 + lane*4);
        c0 = make_float4(bf2f(h0.x), bf2f(h0.y), bf2f(h0.z), bf2f(h0.w));
        c1 = make_float4(bf2f(h1.x), bf2f(h1.y), bf2f(h1.z), bf2f(h1.w));
      } else {
        const float* crow = (const float*)ctx + ((size_t)(b*SS + s))*D;
        c0 = *(const float4*)(crow + lane*4);
        c1 = *(const float4*)(crow + 256 + lane*4);
      }
      *(float4*)&cch[loc][lane*4]       = c0;
      *(float4*)&cch[loc][256 + lane*4] = c1;
      float dot = ur[0]*c0.x + ur[1]*c0.y + ur[2]*c0.z + ur[3]*c0.w
                + ur[4]*c1.x + ur[5]*c1.y + ur[6]*c1.z + ur[7]*c1.w;
      #pragma unroll
      for (int off = 32; off; off >>= 1) dot += __shfl_down(dot, off, 64);
      if (lane == 0) lg[loc] = dot;
    }
    __syncthreads();
    float Mc = lg[0];
    #pragma unroll
    for (int s = 1; s < 16; s++) Mc = fmaxf(Mc, lg[s]);
    float mn = fmaxf(mv, Mc);
    float sc = __expf(mv - mn);
    ls *= sc; o *= sc;
    #pragma unroll
    for (int s = 0; s < 16; s++){
      float e = __expf(lg[s] - mn);
      ls += e;
      o += e * cch[s][tid];
    }
    mv = mn;
    __syncthreads();
  }
  obuf[h*65536 + tid*BB + b] = o;              // unnormalized
  if (tid == 0){
    mlbuf[h*128 + b] = mv;
    mlbuf[256 + h*128 + b] = ls;
  }
}

// merge coefficients for c = a0*o0 + a1*o1
__device__ __forceinline__ void merge_ab(const float* mlbuf, int b, float& a0, float& a1){
  float m0 = mlbuf[b], m1 = mlbuf[128 + b];
  float l0 = mlbuf[256 + b], l1 = mlbuf[384 + b];
  float mm = fmaxf(m0, m1);
  float e0 = __expf(m0 - mm), e1 = __expf(m1 - mm);
  float inv = 1.f / (e0*l0 + e1*l1);
  a0 = e0 * inv; a1 = e1 * inv;
}

// ---------------- K_G2: w += c@W2f (atomic, K-split x4) + preloads ----------------
__global__ __launch_bounds__(256) void k_G2(const float* obuf, const float* mlbuf,
                                            const float* W2f, float* wbuf,
                                            const float* pp2_next, float* u_nxt,
                                            const void* brm, float* mm_nxt,
                                            const void* bwc, float* act_nxt, int t, const int* flag){
  int bk = blockIdx.x, tid = threadIdx.x;
  if (bk < 512){
    int et = bk >> 2, kc = bk & 3;
    int b = tid & 127;
    int ih = __builtin_amdgcn_readfirstlane(tid >> 7);
    int e0 = et*8 + ih*4;
    float a0, a1; merge_ab(mlbuf, b, a0, a1);
    float acc[4] = {0.f, 0.f, 0.f, 0.f};
    int j0 = kc*128;
    for (int j = j0; j < j0 + 128; j += 8){
      float av[8];
      #pragma unroll
      for (int u = 0; u < 8; u++)
        av[u] = a0*obuf[(j+u)*BB + b] + a1*obuf[65536 + (j+u)*BB + b];
      #pragma unroll
      for (int u = 0; u < 8; u++){
        float4 wv = *(const float4*)(W2f + (size_t)(j+u)*D2 + e0);
        acc[0] += av[u]*wv.x; acc[1] += av[u]*wv.y;
        acc[2] += av[u]*wv.z; acc[3] += av[u]*wv.w;
      }
    }
    #pragma unroll
    for (int kk = 0; kk < 4; kk++) atomicAdd(&wbuf[(e0+kk)*BB + b], acc[kk]);
  } else if (bk < 528){
    if (t < TT-1)
      for (int x = (bk-512)*256 + tid; x < D*BB; x += 16*256) u_nxt[x] = pp2_next[x];
  } else if (bk < 544){
    if (t < TT-1){
      const int isbf = *flag;
      for (int x = (bk-528)*256 + tid; x < D*BB; x += 16*256)
        mm_nxt[x] = LDX(brm, x >> 7, isbf);
    }
  } else {
    const int isbf = *flag;
    for (int x = (bk-544)*256 + tid; x < D*BB; x += 16*256)
      act_nxt[D*BB + x] = LDX(bwc, x >> 7, isbf);
  }
}

// ---------------- K_A2a: logits (256 blocks = b x n-half, d-split x4) ----------------
__global__ __launch_bounds__(512) void k_A2a(const void* kmat, const float* wbuf,
                                             const float* mmbuf, float* lgbuf, const int* flag){
  const int isbf = *flag;
  int bk = blockIdx.x, tid = threadIdx.x;
  int b = bk >> 1, h = bk & 1;
  __shared__ float u2[D];
  __shared__ float part[4][128];
  u2[tid] = wbuf[tid*BB + b]*mmbuf[tid*BB + b] + wbuf[(D + tid)*BB + b];
  __syncthreads();
  int n = tid & 127, qd = tid >> 7;
  if (n < 98){
    int ng = h*98 + n;
    float c[8];
    #pragma unroll
    for (int u = 0; u < 8; u++) c[u] = 0.f;
    int d0 = qd*128;
    if (isbf){
      const u16* kb = (const u16*)kmat + (size_t)b*D*NN + ng;
      for (int dd = 0; dd < 128; dd += 8){
        #pragma unroll
        for (int u = 0; u < 8; u++) c[u] += u2[d0+dd+u]*bf2f(kb[(size_t)(d0+dd+u)*NN]);
      }
    } else {
      const float* kb = (const float*)kmat + (size_t)b*D*NN + ng;
      for (int dd = 0; dd < 128; dd += 8){
        #pragma unroll
        for (int u = 0; u < 8; u++) c[u] += u2[d0+dd+u]*kb[(size_t)(d0+dd+u)*NN];
      }
    }
    part[qd][n] = (((c[0]+c[1]) + (c[2]+c[3])) + ((c[4]+c[5]) + (c[6]+c[7])));
  }
  __syncthreads();
  if (tid < 98)
    lgbuf[b*256 + h*98 + tid] = part[0][tid] + part[1][tid] + part[2][tid] + part[3][tid];
}

// ---------------- K_A2b: softmax + r for d-half (256 blocks = b x d-half) ----------------
__global__ __launch_bounds__(512) void k_A2b(const void* kmat, const float* lgbuf,
                                             float* act_cur, const int* flag){
  const int isbf = *flag;
  int bk = blockIdx.x, tid = threadIdx.x;
  int b = bk >> 1, h = bk & 1;
  __shared__ float lg[256];
  __shared__ float red[256];
  if (tid < 256){
    float lv = (tid < NN) ? lgbuf[b*256 + tid] : -INFINITY;
    lg[tid] = lv; red[tid] = lv;
  }
  __syncthreads();
  for (int off = 128; off; off >>= 1){ if (tid < off) red[tid] = fmaxf(red[tid], red[tid+off]); __syncthreads(); }
  float M = red[0];
  __syncthreads();
  if (tid < 256){ float e = (tid < NN) ? __expf(lg[tid] - M) : 0.f; lg[tid] = e; red[tid] = e; }
  __syncthreads();
  for (int off = 128; off; off >>= 1){ if (tid < off) red[tid] += red[tid+off]; __syncthreads(); }
  float inv = 1.f / red[0];
  int lane = tid & 63, wv = tid >> 6;          // 8 waves
  for (int i = 0; i < 16; i++){
    int dA = h*256 + wv + i*16, dB = dA + 8;
    float p, qv;
    if (isbf){
      const u16* krA = (const u16*)kmat + (size_t)b*D*NN + (size_t)dA*NN;
      const u16* krB = (const u16*)kmat + (size_t)b*D*NN + (size_t)dB*NN;
      p  = lg[lane]*bf2f(krA[lane]) + lg[lane+64]*bf2f(krA[lane+64]) + lg[lane+128]*bf2f(krA[lane+128]);
      qv = lg[lane]*bf2f(krB[lane]) + lg[lane+64]*bf2f(krB[lane+64]) + lg[lane+128]*bf2f(krB[lane+128]);
      if (lane < NN - 192){
        p  += lg[lane+192]*bf2f(krA[lane+192]);
        qv += lg[lane+192]*bf2f(krB[lane+192]);
      }
    } else {
      const float* krA = (const float*)kmat + (size_t)b*D*NN + (size_t)dA*NN;
      const float* krB = (const float*)kmat + (size_t)b*D*NN + (size_t)dB*NN;
      p  = lg[lane]*krA[lane] + lg[lane+64]*krA[lane+64] + lg[lane+128]*krA[lane+128];
      qv = lg[lane]*krB[lane] + lg[lane+64]*krB[lane+64] + lg[lane+128]*krB[lane+128];
      if (lane < NN - 192){
        p  += lg[lane+192]*krA[lane+192];
        qv += lg[lane+192]*krB[lane+192];
      }
    }
    #pragma unroll
    for (int off = 32; off; off >>= 1){
      p  += __shfl_down(p , off, 64);
      qv += __shfl_down(qv, off, 64);
    }
    if (lane == 0){
      act_cur[dA*BB + b] = p  * inv;
      act_cur[dB*BB + b] = qv * inv;
    }
  }
}

// ---------------- K_G3: m, u_next (atomic K-split gemvs) + zero wbuf ----------------
__global__ __launch_bounds__(256) void k_G3(const float* act_cur, const float* obuf,
                                            const float* mlbuf,
                                            const float* Wwcf, const float* W1f,
                                            float* act_nxt, float* u_nxt, float* wbuf,
                                            int t){
  int bk = blockIdx.x, tid = threadIdx.x;
  int b = tid & 127;
  int ih = __builtin_amdgcn_readfirstlane(tid >> 7);
  if (bk < 256){
    int it = bk >> 3, kc = bk & 7;
    int i0 = it*16 + ih*8;
    float acc[8] = {0.f,0.f,0.f,0.f,0.f,0.f,0.f,0.f};
    int e0 = kc*128;
    for (int e = e0; e < e0 + 128; e += 8){
      float av[8];
      #pragma unroll
      for (int u = 0; u < 8; u++) av[u] = act_cur[(e+u)*BB + b];
      #pragma unroll
      for (int u = 0; u < 8; u++){
        float4 w0 = *(const float4*)(Wwcf + (size_t)(e+u)*D + i0);
        float4 w1 = *(const float4*)(Wwcf + (size_t)(e+u)*D + i0 + 4);
        acc[0]+=av[u]*w0.x; acc[1]+=av[u]*w0.y; acc[2]+=av[u]*w0.z; acc[3]+=av[u]*w0.w;
        acc[4]+=av[u]*w1.x; acc[5]+=av[u]*w1.y; acc[6]+=av[u]*w1.z; acc[7]+=av[u]*w1.w;
      }
    }
    #pragma unroll
    for (int kk = 0; kk < 8; kk++) atomicAdd(&act_nxt[(size_t)(D + i0 + kk)*BB + b], acc[kk]);
  } else if (bk < 384){
    if (t == TT-1) return;
    int l = bk - 256;
    int it = l >> 2, kc = l & 3;
    int j0 = it*16 + ih*8;
    float a0, a1; merge_ab(mlbuf, b, a0, a1);
    float acc[8] = {0.f,0.f,0.f,0.f,0.f,0.f,0.f,0.f};
    int e0 = kc*128;
    for (int e = e0; e < e0 + 128; e += 8){
      float av[8];
      #pragma unroll
      for (int u = 0; u < 8; u++)
        av[u] = a0*obuf[(e+u)*BB + b] + a1*obuf[65536 + (e+u)*BB + b];
      #pragma unroll
      for (int u = 0; u < 8; u++){
        float4 w0 = *(const float4*)(W1f + (size_t)(e+u)*D + j0);
        float4 w1 = *(const float4*)(W1f + (size_t)(e+u)*D + j0 + 4);
        acc[0]+=av[u]*w0.x; acc[1]+=av[u]*w0.y; acc[2]+=av[u]*w0.z; acc[3]+=av[u]*w0.w;
        acc[4]+=av[u]*w1.x; acc[5]+=av[u]*w1.y; acc[6]+=av[u]*w1.z; acc[7]+=av[u]*w1.w;
      }
    }
    #pragma unroll
    for (int kk = 0; kk < 8; kk++) atomicAdd(&u_nxt[(j0 + kk)*BB + b], acc[kk]);
  } else {
    if (t == TT-1) return;
    for (int x = (bk-384)*256 + tid; x < D2*BB; x += 16*256) wbuf[x] = 0.f;
  }
}

// ---------------- K_out ----------------
__global__ __launch_bounds__(256) void k_out(const float* act_fin, void* out, const int* flag){
  const int isbf = *flag;
  __shared__ float lds[32][33];
  int bk = blockIdx.x;
  int it = bk >> 2, bt = bk & 3;
  int tx = threadIdx.x & 31, ty = threadIdx.x >> 5;
  #pragma unroll
  for (int kk = 0; kk < 4; kk++){
    int i = it*32 + ty + kk*8;
    lds[tx][ty + kk*8] = act_fin[(D + i)*BB + bt*32 + tx];
  }
  __syncthreads();
  if (isbf){
    __hip_bfloat16* o = (__hip_bfloat16*)out;
    #pragma unroll
    for (int kk = 0; kk < 4; kk++){
      int bb = bt*32 + ty + kk*8;
      o[(size_t)bb*D + it*32 + tx] = __float2bfloat16(lds[ty + kk*8][tx]);
    }
  } else {
    float* o = (float*)out;
    #pragma unroll
    for (int kk = 0; kk < 4; kk++){
      int bb = bt*32 + ty + kk*8;
      o[(size_t)bb*D + it*32 + tx] = lds[ty + kk*8][tx];
    }
  }
}

extern "C" void kernel_launch(void* const* d_in, const int* in_sizes, int n_in,
                              void* d_out, int out_size, void* d_ws, size_t ws_size,
                              hipStream_t stream){
  const void* ctx  = d_in[0];
  const void* q    = d_in[1];
  const void* kmat = d_in[2];
  const void* mem0 = d_in[3];
  const void* ctrl0= d_in[4];
  const void* Wp   = d_in[5];
  const void* bp   = d_in[6];
  const void* Wcq  = d_in[7];
  const void* bcq  = d_in[8];
  const void* Wca  = d_in[9];
  const void* Wrm  = d_in[11];
  const void* brm  = d_in[12];
  const void* Wrc  = d_in[13];
  const void* Wra  = d_in[15];
  const void* Wwc  = d_in[17];
  const void* bwc  = d_in[18];

  float* W      = (float*)d_ws;
  float* qT     = W;               // 131072
  float* P      = W + 131072;      // 786432
  float* pp2    = W + 917504;      // 786432
  float* W1f    = W + 1703936;     // 262144
  float* W2f    = W + 1966080;     // 524288
  float* Wwcf   = W + 2490368;     // 524288
  float* WrmTf  = W + 3014656;     // 262144
  float* obuf   = W + 3276800;     // 2 x 65536
  float* mlbuf  = W + 3407872;     // 512
  float* wbuf   = W + 3408384;     // 131072
  float* ubuf   = W + 3539456;     // 2 x 65536
  float* mmbuf  = W + 3670528;     // 2 x 65536
  float* actb   = W + 3801600;     // 2 x 131072
  float* lgbuf  = W + 4063744;     // 32768
  int*   flag   = (int*)(W + 4096512);
  float* ubase  = W + 4096576;     // 512
  float* mmb    = W + 4097088;     // 512

  hipLaunchKernelGGL(k_detect, dim3(1), dim3(256), 0, stream, (const u16*)ctx, flag);
  hipLaunchKernelGGL(k_prep1, dim3(1344), dim3(256), 0, stream,
                     q, Wcq, Wca, Wwc, Wrm, Wrc, Wra, bp, bcq,
                     qT, W1f, Wwcf, WrmTf, W2f, P, pp2, flag);
  hipLaunchKernelGGL(k_P,    dim3(1536), dim3(512), 0, stream, qT, Wp, P, flag);
  hipLaunchKernelGGL(k_pp2,  dim3(768), dim3(512), 0, stream, P, Wcq, Wca, pp2, flag);
  hipLaunchKernelGGL(k_initA, dim3(32), dim3(256), 0, stream,
                     ctrl0, mem0, Wcq, Wca, Wrm, brm, ubase, mmb, flag);
  hipLaunchKernelGGL(k_initB, dim3(160), dim3(256), 0, stream,
                     ubase, mmb, mem0, pp2, ubuf, mmbuf, actb, wbuf, flag);

  for (int t = 0; t < TT; t++){
    int cur = t & 1, nxt = 1 - cur;
    hipLaunchKernelGGL(k_A1, dim3(320), dim3(512), 0, stream,
                       ctx, ubuf + cur*65536, obuf, mlbuf,
                       actb + cur*131072, mmbuf + cur*65536, WrmTf, t, flag);
    hipLaunchKernelGGL(k_G2, dim3(560), dim3(256), 0, stream,
                       obuf, mlbuf, W2f, wbuf,
                       pp2 + ((t+1 < TT) ? (t+1)*65536 : 0), ubuf + nxt*65536,
                       brm, mmbuf + nxt*65536,
                       bwc, actb + nxt*131072, t, flag);
    hipLaunchKernelGGL(k_A2a, dim3(256), dim3(512), 0, stream,
                       kmat, wbuf, mmbuf + cur*65536, lgbuf, flag);
    hipLaunchKernelGGL(k_A2b, dim3(256), dim3(512), 0, stream,
                       kmat, lgbuf, actb + cur*131072, flag);
    hipLaunchKernelGGL(k_G3, dim3(400), dim3(256), 0, stream,
                       actb + cur*131072, obuf, mlbuf, Wwcf, W1f,
                       actb + nxt*131072, ubuf + nxt*65536, wbuf, t);
  }
  hipLaunchKernelGGL(k_out, dim3(64), dim3(256), 0, stream, actb, d_out, flag);
}

// Round 10
// 1224.831 us; speedup vs baseline: 2.7954x; 1.2829x over previous
//
#include <hip/hip_runtime.h>
#include <hip/hip_bf16.h>
#include <cstdint>

#define D  512
#define D2 1024
#define BB 128
#define SS 128
#define NN 196
#define TT 12

typedef unsigned short u16;

__device__ __forceinline__ float bf2f(u16 h){
  union { unsigned int u; float f; } v; v.u = ((unsigned int)h) << 16; return v.f;
}

__device__ __forceinline__ float LDX(const void* p, size_t i, int isbf){
  if (isbf) return bf2f(((const u16*)p)[i]);
  return ((const float*)p)[i];
}

__device__ __forceinline__ float4 LD4(const void* p, size_t i, int isbf){
  if (isbf){
    ushort4 w = *(const ushort4*)((const u16*)p + i);
    return make_float4(bf2f(w.x), bf2f(w.y), bf2f(w.z), bf2f(w.w));
  }
  return *(const float4*)((const float*)p + i);
}

// ---------------- detect input dtype ----------------
__global__ __launch_bounds__(256) void k_detect(const u16* ctx, int* flag){
  __shared__ int cnt;
  if (threadIdx.x == 0) cnt = 0;
  __syncthreads();
  int bad = 0;
  for (int i = threadIdx.x; i < 8192; i += 256){
    int e = (ctx[i] >> 7) & 0xFF;
    if (e == 0xFF || (e != 0 && (e < 90 || e > 160))) bad++;
  }
  atomicAdd(&cnt, bad);
  __syncthreads();
  if (threadIdx.x == 0) *flag = (cnt > 100) ? 0 : 1;   // 1 = bf16, 0 = fp32
}

// ---------------- prep1: transposes / scaled copies + P/pp2 presets ----------------
__global__ __launch_bounds__(256) void k_prep1(const void* q, const void* Wcq, const void* Wca,
      const void* Wwc, const void* Wrm, const void* Wrc, const void* Wra,
      const void* bp, const void* bcq,
      float* qT, float* W1f, float* Wwcf, float* WrmTf, float* W2f,
      float* P, float* pp2, const int* flag){
  const int isbf = *flag;
  __shared__ float lds[32][33];
  int bk = blockIdx.x, tid = threadIdx.x;
  int tx = tid & 31, ty = tid >> 5;
  if (bk >= 1280){                       // pp2 preset = bcq[j]*Wca[j]
    int l = bk - 1280;
    for (int idx = l*256 + tid; idx < 786432; idx += 64*256){
      int j = (idx >> 7) & 511;
      pp2[idx] = LDX(bcq, j, isbf) * LDX(Wca, j, isbf);
    }
    return;
  }
  if (bk >= 1216){                       // P preset = bp
    int l = bk - 1216;
    for (int idx = l*256 + tid; idx < 786432; idx += 64*256)
      P[idx] = LDX(bp, idx >> 7, isbf);
    return;
  }
  if (bk >= 1152){                       // W2f = Wrc * Wra
    int l = bk - 1152;
    if (isbf){
      const u16* w = (const u16*)Wrc; const u16* s = (const u16*)Wra;
      for (int idx = l*256 + tid; idx < 524288; idx += 64*256)
        W2f[idx] = bf2f(w[idx]) * bf2f(s[idx >> 10]);
    } else {
      const float* w = (const float*)Wrc; const float* s = (const float*)Wra;
      for (int idx = l*256 + tid; idx < 524288; idx += 64*256)
        W2f[idx] = w[idx] * s[idx >> 10];
    }
    return;
  }
  const void* in = nullptr; const void* scale = nullptr; float* out = nullptr;
  int ld = 0, R = 0, tR = 0, tC = 0;
  if (bk < 128)      { in = q;   ld = 1024; R = 128; out = qT;    tR = bk & 3;  tC = bk >> 2; }
  else if (bk < 384) { int l = bk - 128; in = Wcq; ld = 1024; R = 512; out = W1f;  scale = Wca; tR = l & 15; tC = l >> 4; }
  else if (bk < 896) { int l = bk - 384; in = Wwc; ld = 1024; R = 512; out = Wwcf; tR = l & 15; tC = l >> 4; }
  else               { int l = bk - 896; in = Wrm; ld = 512;  R = 512; out = WrmTf;tR = l & 15; tC = l >> 4; }
  int r0 = tR*32, c0 = tC*32;
  #pragma unroll
  for (int kk = 0; kk < 4; kk++){
    int r = r0 + ty + kk*8;
    float v = LDX(in, (size_t)r*ld + c0 + tx, isbf);
    if (scale) v *= LDX(scale, r, isbf);
    lds[tx][ty + kk*8] = v;
  }
  __syncthreads();
  #pragma unroll
  for (int kk = 0; kk < 4; kk++){
    int oc = ty + kk*8;
    out[(size_t)(c0 + oc)*R + r0 + tx] = lds[oc][tx];
  }
}

// ---------------- K_P: K-split x4, atomic into bp-preset P ----------------
__global__ __launch_bounds__(512) void k_P(const float* qT, const void* Wp,
                                           float* P, const int* flag){
  const int isbf = *flag;
  int bk = blockIdx.x;                      // 1536 = 12t * 32et * 4kc
  int t = bk >> 7; int r = bk & 127; int et = r >> 2; int kc = r & 3;
  int tid = threadIdx.x;
  int b = tid & 127;
  int ih = __builtin_amdgcn_readfirstlane(tid >> 7);
  int e0 = et*16 + ih*4;
  float acc[4] = {0.f, 0.f, 0.f, 0.f};
  size_t wo = (size_t)(t*D + e0)*D2;
  int x0 = kc*256;
  if (isbf){
    const u16* wb = (const u16*)Wp + wo;
    for (int x = x0; x < x0 + 256; x += 8){
      float a[8];
      #pragma unroll
      for (int u = 0; u < 8; u++) a[u] = qT[(x+u)*BB + b];
      #pragma unroll
      for (int kk = 0; kk < 4; kk++){
        ushort4 w0 = *(const ushort4*)(wb + kk*D2 + x);
        ushort4 w1 = *(const ushort4*)(wb + kk*D2 + x + 4);
        acc[kk] += a[0]*bf2f(w0.x) + a[1]*bf2f(w0.y) + a[2]*bf2f(w0.z) + a[3]*bf2f(w0.w)
                 + a[4]*bf2f(w1.x) + a[5]*bf2f(w1.y) + a[6]*bf2f(w1.z) + a[7]*bf2f(w1.w);
      }
    }
  } else {
    const float* wb = (const float*)Wp + wo;
    for (int x = x0; x < x0 + 256; x += 8){
      float a[8];
      #pragma unroll
      for (int u = 0; u < 8; u++) a[u] = qT[(x+u)*BB + b];
      #pragma unroll
      for (int kk = 0; kk < 4; kk++){
        float4 w0 = *(const float4*)(wb + kk*D2 + x);
        float4 w1 = *(const float4*)(wb + kk*D2 + x + 4);
        acc[kk] += a[0]*w0.x + a[1]*w0.y + a[2]*w0.z + a[3]*w0.w
                 + a[4]*w1.x + a[5]*w1.y + a[6]*w1.z + a[7]*w1.w;
      }
    }
  }
  #pragma unroll
  for (int kk = 0; kk < 4; kk++)
    atomicAdd(&P[(size_t)(t*D + e0 + kk)*BB + b], acc[kk]);
}

// ---------------- K_pp2: K-split x2, atomic into (bcq*Wca)-preset pp2 ----------------
__global__ __launch_bounds__(512) void k_pp2(const float* P, const void* Wcq,
                                             const void* Wca, float* pp2, const int* flag){
  const int isbf = *flag;
  int bk = blockIdx.x;                      // 768 = 12t * 32jt * 2kc
  int t = bk >> 6; int r = bk & 63; int jt = r >> 1; int kc = r & 1;
  int tid = threadIdx.x;
  int b = tid & 127;
  int ih = __builtin_amdgcn_readfirstlane(tid >> 7);
  int j0 = jt*16 + ih*4;
  float acc[4] = {0.f, 0.f, 0.f, 0.f};
  int e0k = kc*256;
  if (isbf){
    const u16* w = (const u16*)Wcq;
    for (int e = e0k; e < e0k + 256; e += 8){
      float a[8];
      #pragma unroll
      for (int u = 0; u < 8; u++) a[u] = P[(size_t)(t*D + e + u)*BB + b];
      #pragma unroll
      for (int kk = 0; kk < 4; kk++){
        ushort4 w0 = *(const ushort4*)(w + (size_t)(j0+kk)*D2 + D + e);
        ushort4 w1 = *(const ushort4*)(w + (size_t)(j0+kk)*D2 + D + e + 4);
        acc[kk] += a[0]*bf2f(w0.x) + a[1]*bf2f(w0.y) + a[2]*bf2f(w0.z) + a[3]*bf2f(w0.w)
                 + a[4]*bf2f(w1.x) + a[5]*bf2f(w1.y) + a[6]*bf2f(w1.z) + a[7]*bf2f(w1.w);
      }
    }
  } else {
    const float* w = (const float*)Wcq;
    for (int e = e0k; e < e0k + 256; e += 8){
      float a[8];
      #pragma unroll
      for (int u = 0; u < 8; u++) a[u] = P[(size_t)(t*D + e + u)*BB + b];
      #pragma unroll
      for (int kk = 0; kk < 4; kk++){
        float4 w0 = *(const float4*)(w + (size_t)(j0+kk)*D2 + D + e);
        float4 w1 = *(const float4*)(w + (size_t)(j0+kk)*D2 + D + e + 4);
        acc[kk] += a[0]*w0.x + a[1]*w0.y + a[2]*w0.z + a[3]*w0.w
                 + a[4]*w1.x + a[5]*w1.y + a[6]*w1.z + a[7]*w1.w;
      }
    }
  }
  #pragma unroll
  for (int kk = 0; kk < 4; kk++)
    atomicAdd(&pp2[(size_t)(t*D + j0 + kk)*BB + b], acc[kk] * LDX(Wca, j0 + kk, isbf));
}

// ---------------- K_initA ----------------
__global__ __launch_bounds__(256) void k_initA(const void* ctrl0, const void* mem0,
                                               const void* Wcq, const void* Wca,
                                               const void* Wrm, const void* brm,
                                               float* ubase, float* mmb, const int* flag){
  const int isbf = *flag;
  int bk = blockIdx.x, tid = threadIdx.x;
  int lane = tid & 63, w = tid >> 6;
  int grp = lane >> 3, k = lane & 7;
  int isU = (bk < 16);
  int o = (isU ? bk : bk - 16)*32 + w*8 + grp;
  const void* vec = isU ? ctrl0 : mem0;
  const void* mat = isU ? Wcq : Wrm;
  int ld = isU ? D2 : D;
  float acc = 0.f;
  #pragma unroll 4
  for (int it = 0; it < 16; it++){
    int d = it*32 + k*4;
    float4 v = LD4(vec, d, isbf);
    float4 m = LD4(mat, (size_t)o*ld + d, isbf);
    acc += v.x*m.x + v.y*m.y + v.z*m.z + v.w*m.w;
  }
  acc += __shfl_xor(acc, 1, 64);
  acc += __shfl_xor(acc, 2, 64);
  acc += __shfl_xor(acc, 4, 64);
  if (k == 0){
    if (isU) ubase[o] = acc * LDX(Wca, o, isbf);
    else     mmb[o]   = acc + LDX(brm, o, isbf);
  }
}

// ---------------- K_initB: u0, mm0, m_{-1} ----------------
__global__ __launch_bounds__(256) void k_initB(const float* ubase, const float* mmb,
                                               const void* mem0, const float* pp2,
                                               float* u0, float* mm0, float* act0,
                                               const int* flag){
  const int isbf = *flag;
  for (int idx = blockIdx.x*256 + threadIdx.x; idx < 3*D*BB; idx += 96*256){
    if (idx < D*BB)            u0[idx] = ubase[idx >> 7] + pp2[idx];
    else if (idx < 2*D*BB)   { int x = idx - D*BB;   mm0[x] = mmb[x >> 7]; }
    else                     { int x = idx - 2*D*BB; act0[D*BB + x] = LDX(mem0, x >> 7, isbf); }
  }
}

// ================ shared attention bodies ================
__device__ void attn1_body(const void* ctx, const float* u_cur, float* cbuf,
                           int b, int tid, int isbf, float* sm){
  float* cch = sm;            // [16][512]
  float* lg  = sm + 8192;     // [16]
  int lane = tid & 63, wv = tid >> 6;
  float ur[8];
  #pragma unroll
  for (int kk = 0; kk < 4; kk++){
    ur[kk]   = u_cur[(lane*4 + kk)*BB + b];
    ur[4+kk] = u_cur[(256 + lane*4 + kk)*BB + b];
  }
  float mv = -INFINITY, ls = 0.f, o = 0.f;     // thread owns d = tid
  for (int c = 0; c < 8; c++){
    int s0 = c*16;
    #pragma unroll
    for (int rr = 0; rr < 2; rr++){
      int loc = rr*8 + wv;
      int s = s0 + loc;
      float4 c0, c1;
      if (isbf){
        const u16* crow = (const u16*)ctx + ((size_t)(b*SS + s))*D;
        ushort4 h0 = *(const ushort4*)(crow + lane*4);
        ushort4 h1 = *(const ushort4*)(crow + 256 + lane*4);
        c0 = make_float4(bf2f(h0.x), bf2f(h0.y), bf2f(h0.z), bf2f(h0.w));
        c1 = make_float4(bf2f(h1.x), bf2f(h1.y), bf2f(h1.z), bf2f(h1.w));
      } else {
        const float* crow = (const float*)ctx + ((size_t)(b*SS + s))*D;
        c0 = *(const float4*)(crow + lane*4);
        c1 = *(const float4*)(crow + 256 + lane*4);
      }
      *(float4*)&cch[loc*512 + lane*4]       = c0;
      *(float4*)&cch[loc*512 + 256 + lane*4] = c1;
      float dot = ur[0]*c0.x + ur[1]*c0.y + ur[2]*c0.z + ur[3]*c0.w
                + ur[4]*c1.x + ur[5]*c1.y + ur[6]*c1.z + ur[7]*c1.w;
      #pragma unroll
      for (int off = 32; off; off >>= 1) dot += __shfl_down(dot, off, 64);
      if (lane == 0) lg[loc] = dot;
    }
    __syncthreads();
    float Mc = lg[0];
    #pragma unroll
    for (int s = 1; s < 16; s++) Mc = fmaxf(Mc, lg[s]);
    float mn = fmaxf(mv, Mc);
    float sc = __expf(mv - mn);
    ls *= sc; o *= sc;
    #pragma unroll
    for (int s = 0; s < 16; s++){
      float e = __expf(lg[s] - mn);
      ls += e;
      o += e * cch[s*512 + tid];
    }
    mv = mn;
    __syncthreads();
  }
  cbuf[tid*BB + b] = o / ls;
}

__device__ void attn2_body(const void* kmat, const float* wbuf, const float* mm_cur,
                           float* act_cur, int b, int tid, int isbf, float* sm){
  float* u2 = sm;           // 512
  float* lg = sm + 512;     // 256
  float* red= sm + 768;     // 256
  float* ps = sm + 1024;    // 2 x 256
  u2[tid] = wbuf[tid*BB + b]*mm_cur[tid*BB + b] + wbuf[(D + tid)*BB + b];
  __syncthreads();
  {
    int half = tid >> 8;
    int n = tid & 255;
    float part = 0.f;
    if (n < NN){
      float c[8];
      #pragma unroll
      for (int u = 0; u < 8; u++) c[u] = 0.f;
      int d0 = half*256;
      if (isbf){
        const u16* kb = (const u16*)kmat + (size_t)b*D*NN + n;
        for (int dd = 0; dd < 256; dd += 8){
          #pragma unroll
          for (int u = 0; u < 8; u++) c[u] += u2[d0+dd+u]*bf2f(kb[(size_t)(d0+dd+u)*NN]);
        }
      } else {
        const float* kb = (const float*)kmat + (size_t)b*D*NN + n;
        for (int dd = 0; dd < 256; dd += 8){
          #pragma unroll
          for (int u = 0; u < 8; u++) c[u] += u2[d0+dd+u]*kb[(size_t)(d0+dd+u)*NN];
        }
      }
      part = (((c[0]+c[1]) + (c[2]+c[3])) + ((c[4]+c[5]) + (c[6]+c[7])));
    }
    ps[half*256 + n] = part;
  }
  __syncthreads();
  if (tid < 256){
    float logit = (tid < NN) ? (ps[tid] + ps[256 + tid]) : -INFINITY;
    lg[tid] = logit; red[tid] = logit;
  }
  __syncthreads();
  for (int off = 128; off; off >>= 1){ if (tid < off) red[tid] = fmaxf(red[tid], red[tid+off]); __syncthreads(); }
  float M = red[0];
  __syncthreads();
  if (tid < 256){ float e = (tid < NN) ? __expf(lg[tid] - M) : 0.f; lg[tid] = e; red[tid] = e; }
  __syncthreads();
  for (int off = 128; off; off >>= 1){ if (tid < off) red[tid] += red[tid+off]; __syncthreads(); }
  float inv = 1.f / red[0];
  int lane = tid & 63, wv = tid >> 6;
  for (int i = 0; i < 32; i++){
    int dA = wv + i*16, dB = dA + 8;
    float p, qv;
    if (isbf){
      const u16* krA = (const u16*)kmat + (size_t)b*D*NN + (size_t)dA*NN;
      const u16* krB = (const u16*)kmat + (size_t)b*D*NN + (size_t)dB*NN;
      p  = lg[lane]*bf2f(krA[lane]) + lg[lane+64]*bf2f(krA[lane+64]) + lg[lane+128]*bf2f(krA[lane+128]);
      qv = lg[lane]*bf2f(krB[lane]) + lg[lane+64]*bf2f(krB[lane+64]) + lg[lane+128]*bf2f(krB[lane+128]);
      if (lane < NN - 192){
        p  += lg[lane+192]*bf2f(krA[lane+192]);
        qv += lg[lane+192]*bf2f(krB[lane+192]);
      }
    } else {
      const float* krA = (const float*)kmat + (size_t)b*D*NN + (size_t)dA*NN;
      const float* krB = (const float*)kmat + (size_t)b*D*NN + (size_t)dB*NN;
      p  = lg[lane]*krA[lane] + lg[lane+64]*krA[lane+64] + lg[lane+128]*krA[lane+128];
      qv = lg[lane]*krB[lane] + lg[lane+64]*krB[lane+64] + lg[lane+128]*krB[lane+128];
      if (lane < NN - 192){
        p  += lg[lane+192]*krA[lane+192];
        qv += lg[lane+192]*krB[lane+192];
      }
    }
    #pragma unroll
    for (int off = 32; off; off >>= 1){
      p  += __shfl_down(p , off, 64);
      qv += __shfl_down(qv, off, 64);
    }
    if (lane == 0){
      act_cur[dA*BB + b] = p  * inv;
      act_cur[dB*BB + b] = qv * inv;
    }
  }
}

// ================ KA: ctx attention + m-gemv + housekeeping ================
// bk<128: attention b=bk -> cbuf (normalized)
// bk in [128,640): t>=1: m_{t-1} = bwc + Wwc^T [r_{t-1}; m_{t-2}] (K-split x16, atomic onto bwc preset)
// bk in [640,704): zero wbuf
// bk in [704,736): t>=1: mmbuf preset = brm
// bk in [736,768): t<TT-1: ubuf_nxt preset = pp2[t+1]
__global__ __launch_bounds__(512) void k_KA(const void* ctx, const float* u_cur, float* cbuf,
                                            const float* act_prev, float* act_cur,
                                            float* wbuf, float* mmbuf, float* u_nxt,
                                            const float* pp2_next, const void* brm,
                                            const float* Wwcf, int t, const int* flag){
  __shared__ float sm[8208];
  int bk = blockIdx.x, tid = threadIdx.x;
  const int isbf = *flag;
  if (bk < 128){
    attn1_body(ctx, u_cur, cbuf, bk, tid, isbf, sm);
    return;
  }
  int b = tid & 127;
  int ih = __builtin_amdgcn_readfirstlane(tid >> 7);   // 0..3
  if (bk < 640){
    if (t == 0) return;
    int l = bk - 128;                    // 0..511
    int it = l >> 3, kc = l & 7;
    int ih0 = ih & 1, ih1 = ih >> 1;
    int i0 = it*8 + ih0*4;
    int e0 = kc*128 + ih1*64;
    float acc[4] = {0.f,0.f,0.f,0.f};
    for (int e = e0; e < e0 + 64; e += 8){
      float av[8];
      #pragma unroll
      for (int u = 0; u < 8; u++) av[u] = act_prev[(size_t)(e+u)*BB + b];
      #pragma unroll
      for (int u = 0; u < 8; u++){
        float4 w0 = *(const float4*)(Wwcf + (size_t)(e+u)*D + i0);
        acc[0]+=av[u]*w0.x; acc[1]+=av[u]*w0.y; acc[2]+=av[u]*w0.z; acc[3]+=av[u]*w0.w;
      }
    }
    #pragma unroll
    for (int kk = 0; kk < 4; kk++)
      atomicAdd(&act_cur[(size_t)(D + i0 + kk)*BB + b], acc[kk]);
  } else if (bk < 704){
    int l = bk - 640;
    for (int x = l*512 + tid; x < D2*BB; x += 64*512) wbuf[x] = 0.f;
  } else if (bk < 736){
    if (t == 0) return;
    int l = bk - 704;
    for (int x = l*512 + tid; x < D*BB; x += 32*512) mmbuf[x] = LDX(brm, x >> 7, isbf);
  } else {
    if (t >= TT-1) return;
    int l = bk - 736;
    for (int x = l*512 + tid; x < D*BB; x += 32*512) u_nxt[x] = pp2_next[x];
  }
}

// ================ KB: w-gemv + mm-gemv (256 thr) ================
// bk<512: wbuf[e,b] += sum_j c[j,b]*W2f[j,e]  (K-split x4, zeroed by KA)
// bk in [512,768): t>=1: mmbuf[i,b] += sum_d WrmTf[d,i]*m_{t-1}[d,b] (K-split x4, brm preset by KA)
__global__ __launch_bounds__(256) void k_KB(const float* cbuf, const float* W2f, float* wbuf,
                                            const float* act_cur, const float* WrmTf,
                                            float* mmbuf, int t){
  int bk = blockIdx.x, tid = threadIdx.x;
  int b = tid & 127;
  int ih = __builtin_amdgcn_readfirstlane(tid >> 7);   // 0..1
  if (bk < 512){
    int et = bk >> 2, kc = bk & 3;
    int e0 = et*8 + ih*4;
    float acc[4] = {0.f, 0.f, 0.f, 0.f};
    int j0 = kc*128;
    for (int j = j0; j < j0 + 128; j += 8){
      float av[8];
      #pragma unroll
      for (int u = 0; u < 8; u++) av[u] = cbuf[(j+u)*BB + b];
      #pragma unroll
      for (int u = 0; u < 8; u++){
        float4 wv = *(const float4*)(W2f + (size_t)(j+u)*D2 + e0);
        acc[0] += av[u]*wv.x; acc[1] += av[u]*wv.y;
        acc[2] += av[u]*wv.z; acc[3] += av[u]*wv.w;
      }
    }
    #pragma unroll
    for (int kk = 0; kk < 4; kk++) atomicAdd(&wbuf[(e0+kk)*BB + b], acc[kk]);
  } else {
    if (t == 0) return;
    int l = bk - 512;
    int it = l >> 2, kc = l & 3;
    int i0 = it*8 + ih*4;
    float acc[4] = {0.f, 0.f, 0.f, 0.f};
    int d0 = kc*128;
    for (int d = d0; d < d0 + 128; d += 8){
      float av[8];
      #pragma unroll
      for (int u = 0; u < 8; u++) av[u] = act_cur[(size_t)(D + d + u)*BB + b];
      #pragma unroll
      for (int u = 0; u < 8; u++){
        float4 wv = *(const float4*)(WrmTf + (size_t)(d+u)*D + i0);
        acc[0] += av[u]*wv.x; acc[1] += av[u]*wv.y;
        acc[2] += av[u]*wv.z; acc[3] += av[u]*wv.w;
      }
    }
    #pragma unroll
    for (int kk = 0; kk < 4; kk++) atomicAdd(&mmbuf[(i0+kk)*BB + b], acc[kk]);
  }
}

// ================ KC: k-attention + u-gemv + bwc preset (512 thr) ================
// bk<128: attn2 -> r into act_cur rows 0..D
// bk in [128,384): t<TT-1: u_nxt[j,b] += sum_e W1f[e,j]*c[e,b] (K-split x2, pp2 preset by KA)
// bk in [384,416): t<TT-1: act_nxt rows D..2D preset = bwc
__global__ __launch_bounds__(512) void k_KC(const void* kmat, const float* wbuf,
                                            const float* mmbuf, float* act_cur,
                                            const float* cbuf, const float* W1f, float* u_nxt,
                                            float* act_nxt, const void* bwc,
                                            int t, const int* flag){
  __shared__ float sm[1536];
  int bk = blockIdx.x, tid = threadIdx.x;
  const int isbf = *flag;
  if (bk < 128){
    attn2_body(kmat, wbuf, mmbuf, act_cur, bk, tid, isbf, sm);
    return;
  }
  int b = tid & 127;
  int ih = __builtin_amdgcn_readfirstlane(tid >> 7);   // 0..3
  if (bk < 384){
    if (t >= TT-1) return;
    int l = bk - 128;                    // 0..255
    int jt = l >> 1, kc = l & 1;
    int j = jt*4 + ih;
    float c0 = 0.f, c1 = 0.f, c2 = 0.f, c3 = 0.f, c4 = 0.f, c5 = 0.f, c6 = 0.f, c7 = 0.f;
    int e0 = kc*256;
    for (int e = e0; e < e0 + 256; e += 8){
      c0 += cbuf[(e  )*BB + b] * W1f[(size_t)(e  )*D + j];
      c1 += cbuf[(e+1)*BB + b] * W1f[(size_t)(e+1)*D + j];
      c2 += cbuf[(e+2)*BB + b] * W1f[(size_t)(e+2)*D + j];
      c3 += cbuf[(e+3)*BB + b] * W1f[(size_t)(e+3)*D + j];
      c4 += cbuf[(e+4)*BB + b] * W1f[(size_t)(e+4)*D + j];
      c5 += cbuf[(e+5)*BB + b] * W1f[(size_t)(e+5)*D + j];
      c6 += cbuf[(e+6)*BB + b] * W1f[(size_t)(e+6)*D + j];
      c7 += cbuf[(e+7)*BB + b] * W1f[(size_t)(e+7)*D + j];
    }
    float acc = (((c0+c1)+(c2+c3)) + ((c4+c5)+(c6+c7)));
    atomicAdd(&u_nxt[(size_t)j*BB + b], acc);
  } else {
    if (t >= TT-1) return;
    int l = bk - 384;
    for (int x = l*512 + tid; x < D*BB; x += 32*512)
      act_nxt[D*BB + x] = LDX(bwc, x >> 7, isbf);
  }
}

// ================ k_mout: final m = bwc + Wwc^T [r_T; m_{T-1}] -> out[b,i] ================
__global__ __launch_bounds__(512) void k_mout(const float* act_fin, const float* Wwcf,
                                              const void* bwc, void* out, const int* flag){
  const int isbf = *flag;
  int bk = blockIdx.x, tid = threadIdx.x;
  int b = tid & 127;
  int ih = __builtin_amdgcn_readfirstlane(tid >> 7);   // 0..3
  int i = bk*4 + ih;
  float c0 = 0.f, c1 = 0.f, c2 = 0.f, c3 = 0.f, c4 = 0.f, c5 = 0.f, c6 = 0.f, c7 = 0.f;
  for (int e = 0; e < D2; e += 8){
    c0 += act_fin[(size_t)(e  )*BB + b] * Wwcf[(size_t)(e  )*D + i];
    c1 += act_fin[(size_t)(e+1)*BB + b] * Wwcf[(size_t)(e+1)*D + i];
    c2 += act_fin[(size_t)(e+2)*BB + b] * Wwcf[(size_t)(e+2)*D + i];
    c3 += act_fin[(size_t)(e+3)*BB + b] * Wwcf[(size_t)(e+3)*D + i];
    c4 += act_fin[(size_t)(e+4)*BB + b] * Wwcf[(size_t)(e+4)*D + i];
    c5 += act_fin[(size_t)(e+5)*BB + b] * Wwcf[(size_t)(e+5)*D + i];
    c6 += act_fin[(size_t)(e+6)*BB + b] * Wwcf[(size_t)(e+6)*D + i];
    c7 += act_fin[(size_t)(e+7)*BB + b] * Wwcf[(size_t)(e+7)*D + i];
  }
  float acc = LDX(bwc, i, isbf) + (((c0+c1)+(c2+c3)) + ((c4+c5)+(c6+c7)));
  if (isbf) ((__hip_bfloat16*)out)[(size_t)b*D + i] = __float2bfloat16(acc);
  else      ((float*)out)[(size_t)b*D + i] = acc;
}

extern "C" void kernel_launch(void* const* d_in, const int* in_sizes, int n_in,
                              void* d_out, int out_size, void* d_ws, size_t ws_size,
                              hipStream_t stream){
  const void* ctx  = d_in[0];
  const void* q    = d_in[1];
  const void* kmat = d_in[2];
  const void* mem0 = d_in[3];
  const void* ctrl0= d_in[4];
  const void* Wp   = d_in[5];
  const void* bp   = d_in[6];
  const void* Wcq  = d_in[7];
  const void* bcq  = d_in[8];
  const void* Wca  = d_in[9];
  const void* Wrm  = d_in[11];
  const void* brm  = d_in[12];
  const void* Wrc  = d_in[13];
  const void* Wra  = d_in[15];
  const void* Wwc  = d_in[17];
  const void* bwc  = d_in[18];

  float* W      = (float*)d_ws;
  float* qT     = W;               // 131072
  float* P      = W + 131072;      // 786432
  float* pp2    = W + 917504;      // 786432
  float* W1f    = W + 1703936;     // 262144
  float* W2f    = W + 1966080;     // 524288
  float* Wwcf   = W + 2490368;     // 524288
  float* WrmTf  = W + 3014656;     // 262144
  float* cbuf   = W + 3276800;     // 65536
  float* wbuf   = W + 3342336;     // 131072
  float* mmbuf  = W + 3473408;     // 65536
  float* actb   = W + 3538944;     // 2 x 131072
  float* ubuf   = W + 3801088;     // 2 x 65536
  int*   flag   = (int*)(W + 3932160);
  float* ubase  = W + 3932224;     // 512
  float* mmb    = W + 3932736;     // 512

  hipLaunchKernelGGL(k_detect, dim3(1), dim3(256), 0, stream, (const u16*)ctx, flag);
  hipLaunchKernelGGL(k_prep1, dim3(1344), dim3(256), 0, stream,
                     q, Wcq, Wca, Wwc, Wrm, Wrc, Wra, bp, bcq,
                     qT, W1f, Wwcf, WrmTf, W2f, P, pp2, flag);
  hipLaunchKernelGGL(k_P,    dim3(1536), dim3(512), 0, stream, qT, Wp, P, flag);
  hipLaunchKernelGGL(k_pp2,  dim3(768), dim3(512), 0, stream, P, Wcq, Wca, pp2, flag);
  hipLaunchKernelGGL(k_initA, dim3(32), dim3(256), 0, stream,
                     ctrl0, mem0, Wcq, Wca, Wrm, brm, ubase, mmb, flag);
  hipLaunchKernelGGL(k_initB, dim3(96), dim3(256), 0, stream,
                     ubase, mmb, mem0, pp2, ubuf, mmbuf, actb, flag);

  for (int t = 0; t < TT; t++){
    int cur = t & 1, nxt = 1 - cur;
    float* act_cur = actb + cur*131072;
    float* act_prev = actb + nxt*131072;   // holds [r_{t-1}; m_{t-2}]
    hipLaunchKernelGGL(k_KA, dim3(768), dim3(512), 0, stream,
                       ctx, ubuf + cur*65536, cbuf,
                       act_prev, act_cur, wbuf, mmbuf, ubuf + nxt*65536,
                       pp2 + ((t+1 < TT) ? (t+1)*65536 : 0), brm, Wwcf, t, flag);
    hipLaunchKernelGGL(k_KB, dim3(768), dim3(256), 0, stream,
                       cbuf, W2f, wbuf, act_cur, WrmTf, mmbuf, t);
    hipLaunchKernelGGL(k_KC, dim3(416), dim3(512), 0, stream,
                       kmat, wbuf, mmbuf, act_cur,
                       cbuf, W1f, ubuf + nxt*65536,
                       act_prev, bwc, t, flag);
  }
  // after t=11 (cur=1): actb[1] = [r_11 ; m_10]
  hipLaunchKernelGGL(k_mout, dim3(128), dim3(512), 0, stream,
                     actb + 131072, Wwcf, bwc, d_out, flag);
}

// Round 11
// 1108.606 us; speedup vs baseline: 3.0884x; 1.1048x over previous
//
#include <hip/hip_runtime.h>
#include <hip/hip_bf16.h>
#include <cstdint>

#define D  512
#define D2 1024
#define BB 128
#define SS 128
#define NN 196
#define TT 12

typedef unsigned short u16;

__device__ __forceinline__ float bf2f(u16 h){
  union { unsigned int u; float f; } v; v.u = ((unsigned int)h) << 16; return v.f;
}

__device__ __forceinline__ float LDX(const void* p, size_t i, int isbf){
  if (isbf) return bf2f(((const u16*)p)[i]);
  return ((const float*)p)[i];
}

__device__ __forceinline__ float4 LD4(const void* p, size_t i, int isbf){
  if (isbf){
    ushort4 w = *(const ushort4*)((const u16*)p + i);
    return make_float4(bf2f(w.x), bf2f(w.y), bf2f(w.z), bf2f(w.w));
  }
  return *(const float4*)((const float*)p + i);
}

// ---------------- detect input dtype ----------------
__global__ __launch_bounds__(256) void k_detect(const u16* ctx, int* flag){
  __shared__ int cnt;
  if (threadIdx.x == 0) cnt = 0;
  __syncthreads();
  int bad = 0;
  for (int i = threadIdx.x; i < 8192; i += 256){
    int e = (ctx[i] >> 7) & 0xFF;
    if (e == 0xFF || (e != 0 && (e < 90 || e > 160))) bad++;
  }
  atomicAdd(&cnt, bad);
  __syncthreads();
  if (threadIdx.x == 0) *flag = (cnt > 100) ? 0 : 1;   // 1 = bf16, 0 = fp32
}

// ---------------- prep1: transposes / scaled copies + P/pp2 presets + initA ----------------
__global__ __launch_bounds__(256) void k_prep1(const void* q, const void* Wcq, const void* Wca,
      const void* Wwc, const void* Wrm, const void* Wrc, const void* Wra,
      const void* bp, const void* bcq, const void* ctrl0, const void* mem0, const void* brm,
      float* qT, float* W1f, float* Wwcf, float* WrmTf, float* W2f,
      float* P, float* pp2, float* ubase, float* mmb, const int* flag){
  const int isbf = *flag;
  __shared__ float lds[32][33];
  int bk = blockIdx.x, tid = threadIdx.x;
  int tx = tid & 31, ty = tid >> 5;
  if (bk >= 1344){                       // initA: 32 blocks
    int ib = bk - 1344;
    int lane = tid & 63, w = tid >> 6;
    int grp = lane >> 3, k = lane & 7;
    int isU = (ib < 16);
    int o = (isU ? ib : ib - 16)*32 + w*8 + grp;
    const void* vec = isU ? ctrl0 : mem0;
    const void* mat = isU ? Wcq : Wrm;
    int ld = isU ? D2 : D;
    float acc = 0.f;
    #pragma unroll 4
    for (int it = 0; it < 16; it++){
      int d = it*32 + k*4;
      float4 v = LD4(vec, d, isbf);
      float4 m = LD4(mat, (size_t)o*ld + d, isbf);
      acc += v.x*m.x + v.y*m.y + v.z*m.z + v.w*m.w;
    }
    acc += __shfl_xor(acc, 1, 64);
    acc += __shfl_xor(acc, 2, 64);
    acc += __shfl_xor(acc, 4, 64);
    if (k == 0){
      if (isU) ubase[o] = acc * LDX(Wca, o, isbf);
      else     mmb[o]   = acc + LDX(brm, o, isbf);
    }
    return;
  }
  if (bk >= 1280){                       // pp2 preset = bcq[j]*Wca[j]
    int l = bk - 1280;
    for (int idx = l*256 + tid; idx < 786432; idx += 64*256){
      int j = (idx >> 7) & 511;
      pp2[idx] = LDX(bcq, j, isbf) * LDX(Wca, j, isbf);
    }
    return;
  }
  if (bk >= 1216){                       // P preset = bp
    int l = bk - 1216;
    for (int idx = l*256 + tid; idx < 786432; idx += 64*256)
      P[idx] = LDX(bp, idx >> 7, isbf);
    return;
  }
  if (bk >= 1152){                       // W2f = Wrc * Wra
    int l = bk - 1152;
    if (isbf){
      const u16* w = (const u16*)Wrc; const u16* s = (const u16*)Wra;
      for (int idx = l*256 + tid; idx < 524288; idx += 64*256)
        W2f[idx] = bf2f(w[idx]) * bf2f(s[idx >> 10]);
    } else {
      const float* w = (const float*)Wrc; const float* s = (const float*)Wra;
      for (int idx = l*256 + tid; idx < 524288; idx += 64*256)
        W2f[idx] = w[idx] * s[idx >> 10];
    }
    return;
  }
  const void* in = nullptr; const void* scale = nullptr; float* out = nullptr;
  int ld = 0, R = 0, tR = 0, tC = 0;
  if (bk < 128)      { in = q;   ld = 1024; R = 128; out = qT;    tR = bk & 3;  tC = bk >> 2; }
  else if (bk < 384) { int l = bk - 128; in = Wcq; ld = 1024; R = 512; out = W1f;  scale = Wca; tR = l & 15; tC = l >> 4; }
  else if (bk < 896) { int l = bk - 384; in = Wwc; ld = 1024; R = 512; out = Wwcf; tR = l & 15; tC = l >> 4; }
  else               { int l = bk - 896; in = Wrm; ld = 512;  R = 512; out = WrmTf;tR = l & 15; tC = l >> 4; }
  int r0 = tR*32, c0 = tC*32;
  #pragma unroll
  for (int kk = 0; kk < 4; kk++){
    int r = r0 + ty + kk*8;
    float v = LDX(in, (size_t)r*ld + c0 + tx, isbf);
    if (scale) v *= LDX(scale, r, isbf);
    lds[tx][ty + kk*8] = v;
  }
  __syncthreads();
  #pragma unroll
  for (int kk = 0; kk < 4; kk++){
    int oc = ty + kk*8;
    out[(size_t)(c0 + oc)*R + r0 + tx] = lds[oc][tx];
  }
}

// ---------------- K_P: K-split x4, x-unroll 16, atomic into bp-preset P ----------------
__global__ __launch_bounds__(512) void k_P(const float* qT, const void* Wp,
                                           float* P, const int* flag){
  const int isbf = *flag;
  int bk = blockIdx.x;                      // 1536 = 12t * 32et * 4kc
  int t = bk >> 7; int r = bk & 127; int et = r >> 2; int kc = r & 3;
  int tid = threadIdx.x;
  int b = tid & 127;
  int ih = __builtin_amdgcn_readfirstlane(tid >> 7);
  int e0 = et*16 + ih*4;
  float acc[4] = {0.f, 0.f, 0.f, 0.f};
  size_t wo = (size_t)(t*D + e0)*D2;
  int x0 = kc*256;
  if (isbf){
    const u16* wb = (const u16*)Wp + wo;
    for (int x = x0; x < x0 + 256; x += 16){
      float a[16];
      #pragma unroll
      for (int u = 0; u < 16; u++) a[u] = qT[(x+u)*BB + b];
      #pragma unroll
      for (int kk = 0; kk < 4; kk++){
        ushort4 w0 = *(const ushort4*)(wb + kk*D2 + x);
        ushort4 w1 = *(const ushort4*)(wb + kk*D2 + x + 4);
        ushort4 w2 = *(const ushort4*)(wb + kk*D2 + x + 8);
        ushort4 w3 = *(const ushort4*)(wb + kk*D2 + x + 12);
        acc[kk] += a[0]*bf2f(w0.x) + a[1]*bf2f(w0.y) + a[2]*bf2f(w0.z) + a[3]*bf2f(w0.w)
                 + a[4]*bf2f(w1.x) + a[5]*bf2f(w1.y) + a[6]*bf2f(w1.z) + a[7]*bf2f(w1.w)
                 + a[8]*bf2f(w2.x) + a[9]*bf2f(w2.y) + a[10]*bf2f(w2.z) + a[11]*bf2f(w2.w)
                 + a[12]*bf2f(w3.x) + a[13]*bf2f(w3.y) + a[14]*bf2f(w3.z) + a[15]*bf2f(w3.w);
      }
    }
  } else {
    const float* wb = (const float*)Wp + wo;
    for (int x = x0; x < x0 + 256; x += 16){
      float a[16];
      #pragma unroll
      for (int u = 0; u < 16; u++) a[u] = qT[(x+u)*BB + b];
      #pragma unroll
      for (int kk = 0; kk < 4; kk++){
        float4 w0 = *(const float4*)(wb + kk*D2 + x);
        float4 w1 = *(const float4*)(wb + kk*D2 + x + 4);
        float4 w2 = *(const float4*)(wb + kk*D2 + x + 8);
        float4 w3 = *(const float4*)(wb + kk*D2 + x + 12);
        acc[kk] += a[0]*w0.x + a[1]*w0.y + a[2]*w0.z + a[3]*w0.w
                 + a[4]*w1.x + a[5]*w1.y + a[6]*w1.z + a[7]*w1.w
                 + a[8]*w2.x + a[9]*w2.y + a[10]*w2.z + a[11]*w2.w
                 + a[12]*w3.x + a[13]*w3.y + a[14]*w3.z + a[15]*w3.w;
      }
    }
  }
  #pragma unroll
  for (int kk = 0; kk < 4; kk++)
    atomicAdd(&P[(size_t)(t*D + e0 + kk)*BB + b], acc[kk]);
}

// ---------------- K_pp2: K-split x2, atomic into (bcq*Wca)-preset pp2 ----------------
__global__ __launch_bounds__(512) void k_pp2(const float* P, const void* Wcq,
                                             const void* Wca, float* pp2, const int* flag){
  const int isbf = *flag;
  int bk = blockIdx.x;                      // 768 = 12t * 32jt * 2kc
  int t = bk >> 6; int r = bk & 63; int jt = r >> 1; int kc = r & 1;
  int tid = threadIdx.x;
  int b = tid & 127;
  int ih = __builtin_amdgcn_readfirstlane(tid >> 7);
  int j0 = jt*16 + ih*4;
  float acc[4] = {0.f, 0.f, 0.f, 0.f};
  int e0k = kc*256;
  if (isbf){
    const u16* w = (const u16*)Wcq;
    for (int e = e0k; e < e0k + 256; e += 8){
      float a[8];
      #pragma unroll
      for (int u = 0; u < 8; u++) a[u] = P[(size_t)(t*D + e + u)*BB + b];
      #pragma unroll
      for (int kk = 0; kk < 4; kk++){
        ushort4 w0 = *(const ushort4*)(w + (size_t)(j0+kk)*D2 + D + e);
        ushort4 w1 = *(const ushort4*)(w + (size_t)(j0+kk)*D2 + D + e + 4);
        acc[kk] += a[0]*bf2f(w0.x) + a[1]*bf2f(w0.y) + a[2]*bf2f(w0.z) + a[3]*bf2f(w0.w)
                 + a[4]*bf2f(w1.x) + a[5]*bf2f(w1.y) + a[6]*bf2f(w1.z) + a[7]*bf2f(w1.w);
      }
    }
  } else {
    const float* w = (const float*)Wcq;
    for (int e = e0k; e < e0k + 256; e += 8){
      float a[8];
      #pragma unroll
      for (int u = 0; u < 8; u++) a[u] = P[(size_t)(t*D + e + u)*BB + b];
      #pragma unroll
      for (int kk = 0; kk < 4; kk++){
        float4 w0 = *(const float4*)(w + (size_t)(j0+kk)*D2 + D + e);
        float4 w1 = *(const float4*)(w + (size_t)(j0+kk)*D2 + D + e + 4);
        acc[kk] += a[0]*w0.x + a[1]*w0.y + a[2]*w0.z + a[3]*w0.w
                 + a[4]*w1.x + a[5]*w1.y + a[6]*w1.z + a[7]*w1.w;
      }
    }
  }
  #pragma unroll
  for (int kk = 0; kk < 4; kk++)
    atomicAdd(&pp2[(size_t)(t*D + j0 + kk)*BB + b], acc[kk] * LDX(Wca, j0 + kk, isbf));
}

// ---------------- K_initB: u0, mm0, m_{-1} ----------------
__global__ __launch_bounds__(256) void k_initB(const float* ubase, const float* mmb,
                                               const void* mem0, const float* pp2,
                                               float* u0, float* mm0, float* act0,
                                               const int* flag){
  const int isbf = *flag;
  for (int idx = blockIdx.x*256 + threadIdx.x; idx < 3*D*BB; idx += 96*256){
    if (idx < D*BB)            u0[idx] = ubase[idx >> 7] + pp2[idx];
    else if (idx < 2*D*BB)   { int x = idx - D*BB;   mm0[x] = mmb[x >> 7]; }
    else                     { int x = idx - 2*D*BB; act0[D*BB + x] = LDX(mem0, x >> 7, isbf); }
  }
}

// ================ shared attention bodies ================
__device__ void attn1_body(const void* ctx, const float* u_cur, float* cbuf,
                           int b, int tid, int isbf, float* sm){
  float* cch = sm;            // [16][512]
  float* lg  = sm + 8192;     // [16]
  int lane = tid & 63, wv = tid >> 6;
  float ur[8];
  #pragma unroll
  for (int kk = 0; kk < 4; kk++){
    ur[kk]   = u_cur[(lane*4 + kk)*BB + b];
    ur[4+kk] = u_cur[(256 + lane*4 + kk)*BB + b];
  }
  float mv = -INFINITY, ls = 0.f, o = 0.f;     // thread owns d = tid
  for (int c = 0; c < 8; c++){
    int s0 = c*16;
    #pragma unroll
    for (int rr = 0; rr < 2; rr++){
      int loc = rr*8 + wv;
      int s = s0 + loc;
      float4 c0, c1;
      if (isbf){
        const u16* crow = (const u16*)ctx + ((size_t)(b*SS + s))*D;
        ushort4 h0 = *(const ushort4*)(crow + lane*4);
        ushort4 h1 = *(const ushort4*)(crow + 256 + lane*4);
        c0 = make_float4(bf2f(h0.x), bf2f(h0.y), bf2f(h0.z), bf2f(h0.w));
        c1 = make_float4(bf2f(h1.x), bf2f(h1.y), bf2f(h1.z), bf2f(h1.w));
      } else {
        const float* crow = (const float*)ctx + ((size_t)(b*SS + s))*D;
        c0 = *(const float4*)(crow + lane*4);
        c1 = *(const float4*)(crow + 256 + lane*4);
      }
      *(float4*)&cch[loc*512 + lane*4]       = c0;
      *(float4*)&cch[loc*512 + 256 + lane*4] = c1;
      float dot = ur[0]*c0.x + ur[1]*c0.y + ur[2]*c0.z + ur[3]*c0.w
                + ur[4]*c1.x + ur[5]*c1.y + ur[6]*c1.z + ur[7]*c1.w;
      #pragma unroll
      for (int off = 32; off; off >>= 1) dot += __shfl_down(dot, off, 64);
      if (lane == 0) lg[loc] = dot;
    }
    __syncthreads();
    float Mc = lg[0];
    #pragma unroll
    for (int s = 1; s < 16; s++) Mc = fmaxf(Mc, lg[s]);
    float mn = fmaxf(mv, Mc);
    float sc = __expf(mv - mn);
    ls *= sc; o *= sc;
    #pragma unroll
    for (int s = 0; s < 16; s++){
      float e = __expf(lg[s] - mn);
      ls += e;
      o += e * cch[s*512 + tid];
    }
    mv = mn;
    __syncthreads();
  }
  cbuf[tid*BB + b] = o / ls;
}

__device__ void attn2_body(const void* kmat, const float* wbuf, const float* mm_cur,
                           float* act_cur, int b, int tid, int isbf, float* sm){
  float* u2 = sm;           // 512
  float* lg = sm + 512;     // 256
  float* red= sm + 768;     // 256
  float* ps = sm + 1024;    // 2 x 256
  u2[tid] = wbuf[tid*BB + b]*mm_cur[tid*BB + b] + wbuf[(D + tid)*BB + b];
  __syncthreads();
  {
    int half = tid >> 8;
    int n = tid & 255;
    float part = 0.f;
    if (n < NN){
      float c[8];
      #pragma unroll
      for (int u = 0; u < 8; u++) c[u] = 0.f;
      int d0 = half*256;
      if (isbf){
        const u16* kb = (const u16*)kmat + (size_t)b*D*NN + n;
        for (int dd = 0; dd < 256; dd += 8){
          #pragma unroll
          for (int u = 0; u < 8; u++) c[u] += u2[d0+dd+u]*bf2f(kb[(size_t)(d0+dd+u)*NN]);
        }
      } else {
        const float* kb = (const float*)kmat + (size_t)b*D*NN + n;
        for (int dd = 0; dd < 256; dd += 8){
          #pragma unroll
          for (int u = 0; u < 8; u++) c[u] += u2[d0+dd+u]*kb[(size_t)(d0+dd+u)*NN];
        }
      }
      part = (((c[0]+c[1]) + (c[2]+c[3])) + ((c[4]+c[5]) + (c[6]+c[7])));
    }
    ps[half*256 + n] = part;
  }
  __syncthreads();
  if (tid < 256){
    float logit = (tid < NN) ? (ps[tid] + ps[256 + tid]) : -INFINITY;
    lg[tid] = logit; red[tid] = logit;
  }
  __syncthreads();
  for (int off = 128; off; off >>= 1){ if (tid < off) red[tid] = fmaxf(red[tid], red[tid+off]); __syncthreads(); }
  float M = red[0];
  __syncthreads();
  if (tid < 256){ float e = (tid < NN) ? __expf(lg[tid] - M) : 0.f; lg[tid] = e; red[tid] = e; }
  __syncthreads();
  for (int off = 128; off; off >>= 1){ if (tid < off) red[tid] += red[tid+off]; __syncthreads(); }
  float inv = 1.f / red[0];
  int lane = tid & 63, wv = tid >> 6;
  for (int i = 0; i < 32; i++){
    int dA = wv + i*16, dB = dA + 8;
    float p, qv;
    if (isbf){
      const u16* krA = (const u16*)kmat + (size_t)b*D*NN + (size_t)dA*NN;
      const u16* krB = (const u16*)kmat + (size_t)b*D*NN + (size_t)dB*NN;
      p  = lg[lane]*bf2f(krA[lane]) + lg[lane+64]*bf2f(krA[lane+64]) + lg[lane+128]*bf2f(krA[lane+128]);
      qv = lg[lane]*bf2f(krB[lane]) + lg[lane+64]*bf2f(krB[lane+64]) + lg[lane+128]*bf2f(krB[lane+128]);
      if (lane < NN - 192){
        p  += lg[lane+192]*bf2f(krA[lane+192]);
        qv += lg[lane+192]*bf2f(krB[lane+192]);
      }
    } else {
      const float* krA = (const float*)kmat + (size_t)b*D*NN + (size_t)dA*NN;
      const float* krB = (const float*)kmat + (size_t)b*D*NN + (size_t)dB*NN;
      p  = lg[lane]*krA[lane] + lg[lane+64]*krA[lane+64] + lg[lane+128]*krA[lane+128];
      qv = lg[lane]*krB[lane] + lg[lane+64]*krB[lane+64] + lg[lane+128]*krB[lane+128];
      if (lane < NN - 192){
        p  += lg[lane+192]*krA[lane+192];
        qv += lg[lane+192]*krB[lane+192];
      }
    }
    #pragma unroll
    for (int off = 32; off; off >>= 1){
      p  += __shfl_down(p , off, 64);
      qv += __shfl_down(qv, off, 64);
    }
    if (lane == 0){
      act_cur[dA*BB + b] = p  * inv;
      act_cur[dB*BB + b] = qv * inv;
    }
  }
}

// ================ KA: ctx attention + m-gemv + housekeeping ================
__global__ __launch_bounds__(512) void k_KA(const void* ctx, const float* u_cur, float* cbuf,
                                            const float* act_prev, float* act_cur,
                                            float* wbuf, float* mmbuf, float* u_nxt,
                                            const float* pp2_next, const void* brm,
                                            const float* Wwcf, int t, const int* flag){
  __shared__ float sm[8208];
  int bk = blockIdx.x, tid = threadIdx.x;
  const int isbf = *flag;
  if (bk < 128){
    attn1_body(ctx, u_cur, cbuf, bk, tid, isbf, sm);
    return;
  }
  int b = tid & 127;
  int ih = __builtin_amdgcn_readfirstlane(tid >> 7);   // 0..3
  if (bk < 640){
    if (t == 0) return;
    int l = bk - 128;                    // 0..511
    int it = l >> 3, kc = l & 7;
    int ih0 = ih & 1, ih1 = ih >> 1;
    int i0 = it*8 + ih0*4;
    int e0 = kc*128 + ih1*64;
    float acc[4] = {0.f,0.f,0.f,0.f};
    for (int e = e0; e < e0 + 64; e += 8){
      float av[8];
      #pragma unroll
      for (int u = 0; u < 8; u++) av[u] = act_prev[(size_t)(e+u)*BB + b];
      #pragma unroll
      for (int u = 0; u < 8; u++){
        float4 w0 = *(const float4*)(Wwcf + (size_t)(e+u)*D + i0);
        acc[0]+=av[u]*w0.x; acc[1]+=av[u]*w0.y; acc[2]+=av[u]*w0.z; acc[3]+=av[u]*w0.w;
      }
    }
    #pragma unroll
    for (int kk = 0; kk < 4; kk++)
      atomicAdd(&act_cur[(size_t)(D + i0 + kk)*BB + b], acc[kk]);
  } else if (bk < 704){
    int l = bk - 640;
    for (int x = l*512 + tid; x < D2*BB; x += 64*512) wbuf[x] = 0.f;
  } else if (bk < 736){
    if (t == 0) return;
    int l = bk - 704;
    for (int x = l*512 + tid; x < D*BB; x += 32*512) mmbuf[x] = LDX(brm, x >> 7, isbf);
  } else {
    if (t >= TT-1) return;
    int l = bk - 736;
    for (int x = l*512 + tid; x < D*BB; x += 32*512) u_nxt[x] = pp2_next[x];
  }
}

// ================ KB: w-gemv + mm-gemv (256 thr) ================
__global__ __launch_bounds__(256) void k_KB(const float* cbuf, const float* W2f, float* wbuf,
                                            const float* act_cur, const float* WrmTf,
                                            float* mmbuf, int t){
  int bk = blockIdx.x, tid = threadIdx.x;
  int b = tid & 127;
  int ih = __builtin_amdgcn_readfirstlane(tid >> 7);   // 0..1
  if (bk < 512){
    int et = bk >> 2, kc = bk & 3;
    int e0 = et*8 + ih*4;
    float acc[4] = {0.f, 0.f, 0.f, 0.f};
    int j0 = kc*128;
    for (int j = j0; j < j0 + 128; j += 8){
      float av[8];
      #pragma unroll
      for (int u = 0; u < 8; u++) av[u] = cbuf[(j+u)*BB + b];
      #pragma unroll
      for (int u = 0; u < 8; u++){
        float4 wv = *(const float4*)(W2f + (size_t)(j+u)*D2 + e0);
        acc[0] += av[u]*wv.x; acc[1] += av[u]*wv.y;
        acc[2] += av[u]*wv.z; acc[3] += av[u]*wv.w;
      }
    }
    #pragma unroll
    for (int kk = 0; kk < 4; kk++) atomicAdd(&wbuf[(e0+kk)*BB + b], acc[kk]);
  } else {
    if (t == 0) return;
    int l = bk - 512;
    int it = l >> 2, kc = l & 3;
    int i0 = it*8 + ih*4;
    float acc[4] = {0.f, 0.f, 0.f, 0.f};
    int d0 = kc*128;
    for (int d = d0; d < d0 + 128; d += 8){
      float av[8];
      #pragma unroll
      for (int u = 0; u < 8; u++) av[u] = act_cur[(size_t)(D + d + u)*BB + b];
      #pragma unroll
      for (int u = 0; u < 8; u++){
        float4 wv = *(const float4*)(WrmTf + (size_t)(d+u)*D + i0);
        acc[0] += av[u]*wv.x; acc[1] += av[u]*wv.y;
        acc[2] += av[u]*wv.z; acc[3] += av[u]*wv.w;
      }
    }
    #pragma unroll
    for (int kk = 0; kk < 4; kk++) atomicAdd(&mmbuf[(i0+kk)*BB + b], acc[kk]);
  }
}

// ================ KC: k-attention + u-gemv + bwc preset (512 thr) ================
__global__ __launch_bounds__(512) void k_KC(const void* kmat, const float* wbuf,
                                            const float* mmbuf, float* act_cur,
                                            const float* cbuf, const float* W1f, float* u_nxt,
                                            float* act_nxt, const void* bwc,
                                            int t, const int* flag){
  __shared__ float sm[1536];
  int bk = blockIdx.x, tid = threadIdx.x;
  const int isbf = *flag;
  if (bk < 128){
    attn2_body(kmat, wbuf, mmbuf, act_cur, bk, tid, isbf, sm);
    return;
  }
  int b = tid & 127;
  int ih = __builtin_amdgcn_readfirstlane(tid >> 7);   // 0..3
  if (bk < 384){
    if (t >= TT-1) return;
    int l = bk - 128;                    // 0..255
    int jt = l >> 1, kc = l & 1;
    int j = jt*4 + ih;
    float c0 = 0.f, c1 = 0.f, c2 = 0.f, c3 = 0.f, c4 = 0.f, c5 = 0.f, c6 = 0.f, c7 = 0.f;
    int e0 = kc*256;
    for (int e = e0; e < e0 + 256; e += 8){
      c0 += cbuf[(e  )*BB + b] * W1f[(size_t)(e  )*D + j];
      c1 += cbuf[(e+1)*BB + b] * W1f[(size_t)(e+1)*D + j];
      c2 += cbuf[(e+2)*BB + b] * W1f[(size_t)(e+2)*D + j];
      c3 += cbuf[(e+3)*BB + b] * W1f[(size_t)(e+3)*D + j];
      c4 += cbuf[(e+4)*BB + b] * W1f[(size_t)(e+4)*D + j];
      c5 += cbuf[(e+5)*BB + b] * W1f[(size_t)(e+5)*D + j];
      c6 += cbuf[(e+6)*BB + b] * W1f[(size_t)(e+6)*D + j];
      c7 += cbuf[(e+7)*BB + b] * W1f[(size_t)(e+7)*D + j];
    }
    float acc = (((c0+c1)+(c2+c3)) + ((c4+c5)+(c6+c7)));
    atomicAdd(&u_nxt[(size_t)j*BB + b], acc);
  } else {
    // bwc preset into act_nxt rows D..2D — runs EVERY step incl. t=11
    // (at t=11 act_nxt = actb[0], consumed only by k_moutA afterwards)
    int l = bk - 384;
    for (int x = l*512 + tid; x < D*BB; x += 32*512)
      act_nxt[D*BB + x] = LDX(bwc, x >> 7, isbf);
  }
}

// ================ k_moutA: m_T = bwc + Wwc^T [r_T; m_{T-1}] (K-split x16) ================
// atomic onto bwc-preset rows D..2D of act_out (= actb[0], preset by KC t=11)
__global__ __launch_bounds__(512) void k_moutA(const float* act_fin, const float* Wwcf,
                                               float* act_out){
  int bk = blockIdx.x, tid = threadIdx.x;   // 512 blocks
  int b = tid & 127;
  int ih = __builtin_amdgcn_readfirstlane(tid >> 7);
  int it = bk >> 3, kc = bk & 7;
  int ih0 = ih & 1, ih1 = ih >> 1;
  int i0 = it*8 + ih0*4;
  int e0 = kc*128 + ih1*64;
  float acc[4] = {0.f,0.f,0.f,0.f};
  for (int e = e0; e < e0 + 64; e += 8){
    float av[8];
    #pragma unroll
    for (int u = 0; u < 8; u++) av[u] = act_fin[(size_t)(e+u)*BB + b];
    #pragma unroll
    for (int u = 0; u < 8; u++){
      float4 w0 = *(const float4*)(Wwcf + (size_t)(e+u)*D + i0);
      acc[0]+=av[u]*w0.x; acc[1]+=av[u]*w0.y; acc[2]+=av[u]*w0.z; acc[3]+=av[u]*w0.w;
    }
  }
  #pragma unroll
  for (int kk = 0; kk < 4; kk++)
    atomicAdd(&act_out[(size_t)(D + i0 + kk)*BB + b], acc[kk]);
}

// ================ k_outT: m[i,b] fp32 -> out[b,i] (bf16 or f32) ================
__global__ __launch_bounds__(256) void k_outT(const float* act_fin, void* out, const int* flag){
  const int isbf = *flag;
  __shared__ float lds[32][33];
  int bk = blockIdx.x;
  int it = bk >> 2, bt = bk & 3;
  int tx = threadIdx.x & 31, ty = threadIdx.x >> 5;
  #pragma unroll
  for (int kk = 0; kk < 4; kk++){
    int i = it*32 + ty + kk*8;
    lds[tx][ty + kk*8] = act_fin[(size_t)(D + i)*BB + bt*32 + tx];
  }
  __syncthreads();
  if (isbf){
    __hip_bfloat16* o = (__hip_bfloat16*)out;
    #pragma unroll
    for (int kk = 0; kk < 4; kk++){
      int bb = bt*32 + ty + kk*8;
      o[(size_t)bb*D + it*32 + tx] = __float2bfloat16(lds[ty + kk*8][tx]);
    }
  } else {
    float* o = (float*)out;
    #pragma unroll
    for (int kk = 0; kk < 4; kk++){
      int bb = bt*32 + ty + kk*8;
      o[(size_t)bb*D + it*32 + tx] = lds[ty + kk*8][tx];
    }
  }
}

extern "C" void kernel_launch(void* const* d_in, const int* in_sizes, int n_in,
                              void* d_out, int out_size, void* d_ws, size_t ws_size,
                              hipStream_t stream){
  const void* ctx  = d_in[0];
  const void* q    = d_in[1];
  const void* kmat = d_in[2];
  const void* mem0 = d_in[3];
  const void* ctrl0= d_in[4];
  const void* Wp   = d_in[5];
  const void* bp   = d_in[6];
  const void* Wcq  = d_in[7];
  const void* bcq  = d_in[8];
  const void* Wca  = d_in[9];
  const void* Wrm  = d_in[11];
  const void* brm  = d_in[12];
  const void* Wrc  = d_in[13];
  const void* Wra  = d_in[15];
  const void* Wwc  = d_in[17];
  const void* bwc  = d_in[18];

  float* W      = (float*)d_ws;
  float* qT     = W;               // 131072
  float* P      = W + 131072;      // 786432
  float* pp2    = W + 917504;      // 786432
  float* W1f    = W + 1703936;     // 262144
  float* W2f    = W + 1966080;     // 524288
  float* Wwcf   = W + 2490368;     // 524288
  float* WrmTf  = W + 3014656;     // 262144
  float* cbuf   = W + 3276800;     // 65536
  float* wbuf   = W + 3342336;     // 131072
  float* mmbuf  = W + 3473408;     // 65536
  float* actb   = W + 3538944;     // 2 x 131072
  float* ubuf   = W + 3801088;     // 2 x 65536
  int*   flag   = (int*)(W + 3932160);
  float* ubase  = W + 3932224;     // 512
  float* mmb    = W + 3932736;     // 512

  hipLaunchKernelGGL(k_detect, dim3(1), dim3(256), 0, stream, (const u16*)ctx, flag);
  hipLaunchKernelGGL(k_prep1, dim3(1376), dim3(256), 0, stream,
                     q, Wcq, Wca, Wwc, Wrm, Wrc, Wra, bp, bcq, ctrl0, mem0, brm,
                     qT, W1f, Wwcf, WrmTf, W2f, P, pp2, ubase, mmb, flag);
  hipLaunchKernelGGL(k_P,    dim3(1536), dim3(512), 0, stream, qT, Wp, P, flag);
  hipLaunchKernelGGL(k_pp2,  dim3(768), dim3(512), 0, stream, P, Wcq, Wca, pp2, flag);
  hipLaunchKernelGGL(k_initB, dim3(96), dim3(256), 0, stream,
                     ubase, mmb, mem0, pp2, ubuf, mmbuf, actb, flag);

  for (int t = 0; t < TT; t++){
    int cur = t & 1, nxt = 1 - cur;
    float* act_cur = actb + cur*131072;
    float* act_prev = actb + nxt*131072;   // holds [r_{t-1}; m_{t-2}]
    hipLaunchKernelGGL(k_KA, dim3(768), dim3(512), 0, stream,
                       ctx, ubuf + cur*65536, cbuf,
                       act_prev, act_cur, wbuf, mmbuf, ubuf + nxt*65536,
                       pp2 + ((t+1 < TT) ? (t+1)*65536 : 0), brm, Wwcf, t, flag);
    hipLaunchKernelGGL(k_KB, dim3(768), dim3(256), 0, stream,
                       cbuf, W2f, wbuf, act_cur, WrmTf, mmbuf, t);
    hipLaunchKernelGGL(k_KC, dim3(416), dim3(512), 0, stream,
                       kmat, wbuf, mmbuf, act_cur,
                       cbuf, W1f, ubuf + nxt*65536,
                       actb + nxt*131072, bwc, t, flag);
  }
  // after t=11 (cur=1): actb[1] = [r_11 ; m_10]; actb[0] rows D..2D preset = bwc (KC t=11)
  hipLaunchKernelGGL(k_moutA, dim3(512), dim3(512), 0, stream,
                     actb + 131072, Wwcf, actb);
  hipLaunchKernelGGL(k_outT, dim3(64), dim3(256), 0, stream, actb, d_out, flag);
}